// Round 1
// baseline (232.187 us; speedup 1.0000x reference)
//
#include <hip/hip_runtime.h>

#define C_ 64
#define H_ 128
#define W_ 128
#define B_ 8
#define HW_ (H_*W_)
#define NPIX (B_*HW_)

typedef _Float16 half8 __attribute__((ext_vector_type(8)));
typedef float floatx4 __attribute__((ext_vector_type(4)));
// 4-B-aligned pair for bilinear corner loads (x0,x0+1 adjacent in memory).
struct f2 { float x, y; };

// ---------------------------------------------------------------------------
// Prep: pack offset/mask weights into contiguous per-channel rows
// wOffAll[c][56] (wide wave-uniform s_loads) and cast deform weights to f16.
// ---------------------------------------------------------------------------
__global__ __launch_bounds__(256) void prep_kernel(
    const float* __restrict__ w_off_h, const float* __restrict__ w_mask_h,
    const float* __restrict__ w_off_v, const float* __restrict__ w_mask_v,
    const float* __restrict__ w_h, const float* __restrict__ w_v,
    float* __restrict__ wOffAll, _Float16* __restrict__ wF16_h,
    _Float16* __restrict__ wF16_v)
{
    int gid = blockIdx.x * 256 + threadIdx.x;
    if (gid < 64 * 56) {
        int c = gid / 56, idx = gid - 56 * c;
        float v = 0.f;
        if (idx < 18)      v = w_off_h [((idx      ) / 3) * 192 + c * 3 + (idx      ) % 3];
        else if (idx < 27) v = w_mask_h[((idx - 18) / 3) * 192 + c * 3 + (idx - 18) % 3];
        else if (idx < 45) v = w_off_v [((idx - 27) / 3) * 192 + c * 3 + (idx - 27) % 3];
        else if (idx < 54) v = w_mask_v[((idx - 45) / 3) * 192 + c * 3 + (idx - 45) % 3];
        wOffAll[c * 56 + idx] = v;
    } else if (gid < 3584 + 12288) {
        int i = gid - 3584;
        wF16_h[i] = (_Float16)w_h[i];
    } else if (gid < 3584 + 24576) {
        int i = gid - 3584 - 12288;
        wF16_v[i] = (_Float16)w_v[i];
    }
}

// ---------------------------------------------------------------------------
// Bilinear tap -> paired-load form (round-6 verified). 2 pair-loads + 4 FMAs
// per (channel, tap); edge validity folded into pair weights.
// ---------------------------------------------------------------------------
__device__ __forceinline__ void tap_setup(
    float fi, float fj, float dy, float dx, float m, float kyo, float kxo,
    int& b0, int& b1, float& wA0, float& wB0, float& wA1, float& wB1)
{
    float py = fi + kyo + dy;
    float px = fj + kxo + dx;
    float y0f = floorf(py), x0f = floorf(px);
    float wy = py - y0f, wx = px - x0f;
    int y0 = (int)y0f, x0 = (int)x0f;
    int y1 = y0 + 1, x1 = x0 + 1;
    bool vy0 = (y0 >= 0) && (y0 < H_);
    bool vy1 = (y1 >= 0) && (y1 < H_);
    bool vx0 = (x0 >= 0) && (x0 < W_);
    bool vx1 = (x1 >= 0) && (x1 < W_);
    int y0c = min(max(y0, 0), H_ - 1), y1c = min(max(y1, 0), H_ - 1);
    int xb = min(max(x0, 0), W_ - 2);
    int s0 = min(max(x0 - xb, 0), 1);      // v00 = pair[s0]
    int s1 = min(max(x1 - xb, 0), 1);      // v01 = pair[s1]
    float wy1 = 1.f - wy, wx1 = 1.f - wx;
    float w00 = (vy0 && vx0) ? wy1 * wx1 * m : 0.f;
    float w01 = (vy0 && vx1) ? wy1 * wx  * m : 0.f;
    float w10 = (vy1 && vx0) ? wy  * wx1 * m : 0.f;
    float w11 = (vy1 && vx1) ? wy  * wx  * m : 0.f;
    wA0 = (s0 ? 0.f : w00) + (s1 ? 0.f : w01);
    wB0 = (s0 ? w00 : 0.f) + (s1 ? w01 : 0.f);
    wA1 = (s0 ? 0.f : w10) + (s1 ? 0.f : w11);
    wB1 = (s0 ? w10 : 0.f) + (s1 ? w11 : 0.f);
    b0 = y0c * W_ + xb;
    b1 = y1c * W_ + xb;
}

// XCD-aware swizzle: one image (n) = 4 MB = exactly one XCD's L2. Blocks go
// to XCDs round-robin by blockIdx%8, so n = bid&7 pins image k to XCD k and
// kills the 4.3x cross-XCD HBM re-fetch (round-6: FETCH 144 MB vs 33.5 MB
// unique; gathers miss to HBM at ~900 cyc instead of L2-hit ~200 cyc).
#define SWIZZLE_NP()                        \
    int bid = blockIdx.x;                   \
    int n   = bid & 7;                      \
    int m   = bid >> 3;      /* 0..255 in-image tile */ \
    int pix = m * 64 + lane;                \
    int j = pix & (W_ - 1);                 \
    int i = pix >> 7;

// ---------------------------------------------------------------------------
// Fused horizontal pass: offs prologue (h offsets kept in LDS, v written to
// ws) + deformable (1,K) conv via MFMA.
// Round-7: explicit load staging — issue wide batches of independent loads
// (40 in prologue, 24 per gather batch) before consuming, to cut exposed
// L2/L3 latency (kernel was latency-bound: VALUBusy 17%, MFMA 1.5%, HBM 8%).
// ---------------------------------------------------------------------------
__global__ __launch_bounds__(256, 4) void deform_h_kernel(
    const float* __restrict__ x, const float* __restrict__ wOffAll,
    const float* __restrict__ b_off_h, const float* __restrict__ b_mask_h,
    const float* __restrict__ b_off_v, const float* __restrict__ b_mask_v,
    const _Float16* __restrict__ wF16, const float* __restrict__ bias,
    float* __restrict__ off_v, float* __restrict__ mask_v,
    float* __restrict__ out)
{
    __shared__ __align__(16) char smem[25600];
    float (*red)[18][64] = reinterpret_cast<float(*)[18][64]>(smem);
    _Float16 (*valT)[200] = reinterpret_cast<_Float16(*)[200]>(smem);

    int lane = threadIdx.x & 63;
    int wv   = threadIdx.x >> 6;
    int c0 = __builtin_amdgcn_readfirstlane(wv << 4);   // SGPR slice base

    SWIZZLE_NP();

    // ---- offs prologue: 5-pt stencil over this wave's 16 channels ----
    float a[18];
    #pragma unroll
    for (int o = 0; o < 18; ++o) a[o] = 0.f;

    const float* xs = x + (size_t)n * C_ * HW_ + (size_t)c0 * HW_;
    for (int cb = 0; cb < 16; cb += 8) {
        // stage 8 channels x 5 stencil points = 40 independent loads
        float xc[8], xl[8], xr[8], xu[8], xd[8];
        #pragma unroll
        for (int q = 0; q < 8; ++q) {
            const float* s = xs + (cb + q) * HW_;
            xc[q] = s[pix];
            xl[q] = (j > 0)      ? s[pix - 1]  : 0.f;
            xr[q] = (j < W_ - 1) ? s[pix + 1]  : 0.f;
            xu[q] = (i > 0)      ? s[pix - W_] : 0.f;
            xd[q] = (i < H_ - 1) ? s[pix + W_] : 0.f;
        }
        #pragma unroll
        for (int q = 0; q < 8; ++q) {
            const float* wc = wOffAll + (c0 + cb + q) * 56;   // uniform -> s_load
            #pragma unroll
            for (int o = 0; o < 6; ++o) {
                a[o]   = fmaf(xl[q], wc[3*o],    fmaf(xc[q], wc[3*o+1],    fmaf(xr[q], wc[3*o+2],    a[o])));
                a[9+o] = fmaf(xu[q], wc[27+3*o], fmaf(xc[q], wc[27+3*o+1], fmaf(xd[q], wc[27+3*o+2], a[9+o])));
            }
            #pragma unroll
            for (int o = 0; o < 3; ++o) {
                a[6+o]  = fmaf(xl[q], wc[18+3*o], fmaf(xc[q], wc[18+3*o+1], fmaf(xr[q], wc[18+3*o+2], a[6+o])));
                a[15+o] = fmaf(xu[q], wc[45+3*o], fmaf(xc[q], wc[45+3*o+1], fmaf(xd[q], wc[45+3*o+2], a[15+o])));
            }
        }
    }

    // ---- cross-wave reduce: h-set -> LDS (consumed below), v-set -> ws ----
    #pragma unroll
    for (int o = 0; o < 18; ++o) red[wv][o][lane] = a[o];
    __syncthreads();

    for (int v = threadIdx.x; v < 18 * 64; v += 256) {
        int idx = v >> 6;
        int px  = v & 63;
        float sum = red[0][idx][px] + red[1][idx][px]
                  + red[2][idx][px] + red[3][idx][px];
        int pixg = m * 64 + px;
        if (idx < 6) {
            red[0][idx][px] = sum + b_off_h[idx];    // (idx,px) has unique owner
        } else if (idx < 9) {
            red[0][idx][px] = 1.f / (1.f + __expf(-(sum + b_mask_h[idx - 6])));
        } else if (idx < 15) {
            // streaming, read once by v-kernel: keep out of this XCD's L2
            __builtin_nontemporal_store(sum + b_off_v[idx - 9],
                &off_v[((size_t)n * 6 + (idx - 9)) * HW_ + pixg]);
        } else {
            __builtin_nontemporal_store(
                1.f / (1.f + __expf(-(sum + b_mask_v[idx - 15]))),
                &mask_v[((size_t)n * 3 + (idx - 15)) * HW_ + pixg]);
        }
    }
    __syncthreads();

    float dyk[3], dxk[3], mk[3];
    #pragma unroll
    for (int k = 0; k < 3; ++k) {
        dyk[k] = red[0][2*k    ][lane];
        dxk[k] = red[0][2*k + 1][lane];
        mk [k] = red[0][6 + k  ][lane];
    }
    __syncthreads();   // all reads of red done before valT overwrites smem

    // ---- tap setup (horizontal: kyo=0, kxo=k-1) ----
    int b0[3], b1[3];
    float wA0[3], wB0[3], wA1[3], wB1[3];
    #pragma unroll
    for (int k = 0; k < 3; ++k)
        tap_setup((float)i, (float)j, dyk[k], dxk[k], mk[k], 0.f, (float)(k - 1),
                  b0[k], b1[k], wA0[k], wB0[k], wA1[k], wB1[k]);

    // ---- phase 1: paired gathers -> f16 -> LDS (staged, 24 loads/batch) ----
    #pragma unroll
    for (int g = 0; g < 2; ++g) {
        half8 t8[3];
        #pragma unroll
        for (int hh = 0; hh < 2; ++hh) {
            f2 p0[4][3], p1[4][3];
            #pragma unroll
            for (int q = 0; q < 4; ++q) {
                const float* s = xs + (g * 8 + hh * 4 + q) * HW_;
                #pragma unroll
                for (int k = 0; k < 3; ++k) {
                    p0[q][k] = *(const f2*)(s + b0[k]);
                    p1[q][k] = *(const f2*)(s + b1[k]);
                }
            }
            #pragma unroll
            for (int q = 0; q < 4; ++q) {
                #pragma unroll
                for (int k = 0; k < 3; ++k) {
                    float v = fmaf(wA0[k], p0[q][k].x, fmaf(wB0[k], p0[q][k].y,
                              fmaf(wA1[k], p1[q][k].x, wB1[k] * p1[q][k].y)));
                    int t = (hh * 4 + q) * 3 + k;
                    t8[t >> 3][t & 7] = (_Float16)v;
                }
            }
        }
        #pragma unroll
        for (int w = 0; w < 3; ++w)
            *((half8*)&valT[lane][wv * 48 + g * 24 + w * 8]) = t8[w];
    }
    __syncthreads();

    // ---- phase 2: MFMA contraction (round-5 verified layout) ----
    const _Float16* wpA = wF16 + (size_t)(c0 + (lane & 15)) * 192 + ((lane >> 4) << 3);
    half8 A0 = *((const half8*)(wpA +   0));
    half8 A1 = *((const half8*)(wpA +  32));
    half8 A2 = *((const half8*)(wpA +  64));
    half8 A3 = *((const half8*)(wpA +  96));
    half8 A4 = *((const half8*)(wpA + 128));
    half8 A5 = *((const half8*)(wpA + 160));

    int col  = lane & 15;
    int orow = c0 + ((lane >> 4) << 2);
    floatx4 bv = *((const floatx4*)&bias[orow]);
    float* ob = out + ((size_t)n * C_ + orow) * HW_ + m * 64 + col;

#define TILE(T)                                                               \
    {                                                                         \
        const _Float16* bp = &valT[(T) * 16 + col][(lane >> 4) << 3];         \
        floatx4 acc = {0.f, 0.f, 0.f, 0.f};                                   \
        acc = __builtin_amdgcn_mfma_f32_16x16x32_f16(A0, *((const half8*)(bp +   0)), acc, 0, 0, 0); \
        acc = __builtin_amdgcn_mfma_f32_16x16x32_f16(A1, *((const half8*)(bp +  32)), acc, 0, 0, 0); \
        acc = __builtin_amdgcn_mfma_f32_16x16x32_f16(A2, *((const half8*)(bp +  64)), acc, 0, 0, 0); \
        acc = __builtin_amdgcn_mfma_f32_16x16x32_f16(A3, *((const half8*)(bp +  96)), acc, 0, 0, 0); \
        acc = __builtin_amdgcn_mfma_f32_16x16x32_f16(A4, *((const half8*)(bp + 128)), acc, 0, 0, 0); \
        acc = __builtin_amdgcn_mfma_f32_16x16x32_f16(A5, *((const half8*)(bp + 160)), acc, 0, 0, 0); \
        ob[(T) * 16 + (size_t)0 * HW_] = acc[0] + bv[0];                      \
        ob[(T) * 16 + (size_t)1 * HW_] = acc[1] + bv[1];                      \
        ob[(T) * 16 + (size_t)2 * HW_] = acc[2] + bv[2];                      \
        ob[(T) * 16 + (size_t)3 * HW_] = acc[3] + bv[3];                      \
    }

    TILE(0)
    TILE(1)
    TILE(2)
    TILE(3)
#undef TILE
}

// ---------------------------------------------------------------------------
// Vertical pass: deformable (K,1) conv on x_h; offsets/masks precomputed.
// Same swizzle (x_h layout identical to x). Staged gathers as in h-kernel;
// final out stores are non-temporal (never re-read) so x_h stays L2-hot
// for the gathers.
// ---------------------------------------------------------------------------
__global__ __launch_bounds__(256, 4) void deform_v_kernel(
    const float* __restrict__ src, const float* __restrict__ off,
    const float* __restrict__ mask, const _Float16* __restrict__ wF16,
    const float* __restrict__ bias, float* __restrict__ out)
{
    __shared__ __align__(16) _Float16 valT[64][200];

    int lane = threadIdx.x & 63;
    int wv   = threadIdx.x >> 6;
    int c0 = __builtin_amdgcn_readfirstlane(wv << 4);

    SWIZZLE_NP();

    int b0[3], b1[3];
    float wA0[3], wB0[3], wA1[3], wB1[3];
    #pragma unroll
    for (int k = 0; k < 3; ++k) {
        float dy = off[(((size_t)n * 3 + k) * 2 + 0) * HW_ + pix];
        float dx = off[(((size_t)n * 3 + k) * 2 + 1) * HW_ + pix];
        float m_ = mask[((size_t)n * 3 + k) * HW_ + pix];
        tap_setup((float)i, (float)j, dy, dx, m_, (float)(k - 1), 0.f,
                  b0[k], b1[k], wA0[k], wB0[k], wA1[k], wB1[k]);
    }

    const float* sb = src + (size_t)n * C_ * HW_ + (size_t)c0 * HW_;
    #pragma unroll
    for (int g = 0; g < 2; ++g) {
        half8 t8[3];
        #pragma unroll
        for (int hh = 0; hh < 2; ++hh) {
            f2 p0[4][3], p1[4][3];
            #pragma unroll
            for (int q = 0; q < 4; ++q) {
                const float* s = sb + (g * 8 + hh * 4 + q) * HW_;
                #pragma unroll
                for (int k = 0; k < 3; ++k) {
                    p0[q][k] = *(const f2*)(s + b0[k]);
                    p1[q][k] = *(const f2*)(s + b1[k]);
                }
            }
            #pragma unroll
            for (int q = 0; q < 4; ++q) {
                #pragma unroll
                for (int k = 0; k < 3; ++k) {
                    float v = fmaf(wA0[k], p0[q][k].x, fmaf(wB0[k], p0[q][k].y,
                              fmaf(wA1[k], p1[q][k].x, wB1[k] * p1[q][k].y)));
                    int t = (hh * 4 + q) * 3 + k;
                    t8[t >> 3][t & 7] = (_Float16)v;
                }
            }
        }
        #pragma unroll
        for (int w = 0; w < 3; ++w)
            *((half8*)&valT[lane][wv * 48 + g * 24 + w * 8]) = t8[w];
    }
    __syncthreads();

    const _Float16* wpA = wF16 + (size_t)(c0 + (lane & 15)) * 192 + ((lane >> 4) << 3);
    half8 A0 = *((const half8*)(wpA +   0));
    half8 A1 = *((const half8*)(wpA +  32));
    half8 A2 = *((const half8*)(wpA +  64));
    half8 A3 = *((const half8*)(wpA +  96));
    half8 A4 = *((const half8*)(wpA + 128));
    half8 A5 = *((const half8*)(wpA + 160));

    int col  = lane & 15;
    int orow = c0 + ((lane >> 4) << 2);
    floatx4 bv = *((const floatx4*)&bias[orow]);
    float* ob = out + ((size_t)n * C_ + orow) * HW_ + m * 64 + col;

#define TILE(T)                                                               \
    {                                                                         \
        const _Float16* bp = &valT[(T) * 16 + col][(lane >> 4) << 3];         \
        floatx4 acc = {0.f, 0.f, 0.f, 0.f};                                   \
        acc = __builtin_amdgcn_mfma_f32_16x16x32_f16(A0, *((const half8*)(bp +   0)), acc, 0, 0, 0); \
        acc = __builtin_amdgcn_mfma_f32_16x16x32_f16(A1, *((const half8*)(bp +  32)), acc, 0, 0, 0); \
        acc = __builtin_amdgcn_mfma_f32_16x16x32_f16(A2, *((const half8*)(bp +  64)), acc, 0, 0, 0); \
        acc = __builtin_amdgcn_mfma_f32_16x16x32_f16(A3, *((const half8*)(bp +  96)), acc, 0, 0, 0); \
        acc = __builtin_amdgcn_mfma_f32_16x16x32_f16(A4, *((const half8*)(bp + 128)), acc, 0, 0, 0); \
        acc = __builtin_amdgcn_mfma_f32_16x16x32_f16(A5, *((const half8*)(bp + 160)), acc, 0, 0, 0); \
        __builtin_nontemporal_store(acc[0] + bv[0], &ob[(T) * 16 + (size_t)0 * HW_]); \
        __builtin_nontemporal_store(acc[1] + bv[1], &ob[(T) * 16 + (size_t)1 * HW_]); \
        __builtin_nontemporal_store(acc[2] + bv[2], &ob[(T) * 16 + (size_t)2 * HW_]); \
        __builtin_nontemporal_store(acc[3] + bv[3], &ob[(T) * 16 + (size_t)3 * HW_]); \
    }

    TILE(0)
    TILE(1)
    TILE(2)
    TILE(3)
#undef TILE
}

// ---------------------------------------------------------------------------
extern "C" void kernel_launch(void* const* d_in, const int* in_sizes, int n_in,
                              void* d_out, int out_size, void* d_ws, size_t ws_size,
                              hipStream_t stream)
{
    const float* x        = (const float*)d_in[0];
    const float* w_off_h  = (const float*)d_in[1];
    const float* b_off_h  = (const float*)d_in[2];
    const float* w_mask_h = (const float*)d_in[3];
    const float* b_mask_h = (const float*)d_in[4];
    const float* w_off_v  = (const float*)d_in[5];
    const float* b_off_v  = (const float*)d_in[6];
    const float* w_mask_v = (const float*)d_in[7];
    const float* b_mask_v = (const float*)d_in[8];
    const float* w_h      = (const float*)d_in[9];
    const float* b_h      = (const float*)d_in[10];
    const float* w_v      = (const float*)d_in[11];
    const float* b_v      = (const float*)d_in[12];

    float* ws      = (float*)d_ws;
    float* off_v   = ws;                    // 786432
    float* mask_v  = off_v  + 786432;       // 393216
    float* x_h     = mask_v + 393216;       // 8388608
    float* wOffAll = x_h    + 8388608;      // 3584
    _Float16* wF16_h = (_Float16*)(wOffAll + 3584);  // 12288 halfs
    _Float16* wF16_v = wF16_h + 12288;               // 12288 halfs

    prep_kernel<<<110, 256, 0, stream>>>(
        w_off_h, w_mask_h, w_off_v, w_mask_v, w_h, w_v,
        wOffAll, wF16_h, wF16_v);

    dim3 grid(NPIX / 64), block(256);
    deform_h_kernel<<<grid, block, 0, stream>>>(
        x, wOffAll, b_off_h, b_mask_h, b_off_v, b_mask_v,
        wF16_h, b_h, off_v, mask_v, x_h);

    deform_v_kernel<<<grid, block, 0, stream>>>(
        x_h, off_v, mask_v, wF16_v, b_v, (float*)d_out);
}

// Round 2
// 225.525 us; speedup vs baseline: 1.0295x; 1.0295x over previous
//
#include <hip/hip_runtime.h>

#define C_ 64
#define H_ 128
#define W_ 128
#define B_ 8
#define HW_ (H_*W_)
#define NPIX (B_*HW_)

typedef _Float16 half8 __attribute__((ext_vector_type(8)));
typedef float floatx4 __attribute__((ext_vector_type(4)));
// 4-B-aligned pair for bilinear corner loads (x0,x0+1 adjacent in memory).
struct f2 { float x, y; };

// ---------------------------------------------------------------------------
// Prep: pack offset/mask weights into contiguous per-channel rows
// wOffAll[c][56] (wide wave-uniform s_loads) and cast deform weights to f16.
// Round-8: deform weights stored with K-dim PERMUTED for split-K MFMA:
//   K'(c,k) = g*96 + wv*24 + cl*3 + k   where c = wv*16 + g*8 + cl.
// Round r of the MFMA phase consumes K' = r*96 .. r*96+95, which is exactly
// the g=r gather output of all 4 waves. MFMA fragment layout unchanged.
// ---------------------------------------------------------------------------
__global__ __launch_bounds__(256) void prep_kernel(
    const float* __restrict__ w_off_h, const float* __restrict__ w_mask_h,
    const float* __restrict__ w_off_v, const float* __restrict__ w_mask_v,
    const float* __restrict__ w_h, const float* __restrict__ w_v,
    float* __restrict__ wOffAll, _Float16* __restrict__ wF16_h,
    _Float16* __restrict__ wF16_v)
{
    int gid = blockIdx.x * 256 + threadIdx.x;
    if (gid < 64 * 56) {
        int c = gid / 56, idx = gid - 56 * c;
        float v = 0.f;
        if (idx < 18)      v = w_off_h [((idx      ) / 3) * 192 + c * 3 + (idx      ) % 3];
        else if (idx < 27) v = w_mask_h[((idx - 18) / 3) * 192 + c * 3 + (idx - 18) % 3];
        else if (idx < 45) v = w_off_v [((idx - 27) / 3) * 192 + c * 3 + (idx - 27) % 3];
        else if (idx < 54) v = w_mask_v[((idx - 45) / 3) * 192 + c * 3 + (idx - 45) % 3];
        wOffAll[c * 56 + idx] = v;
    } else if (gid < 3584 + 24576) {
        int i = gid - 3584;
        const float* srcw = w_h;
        _Float16* dstw = wF16_h;
        if (i >= 12288) { i -= 12288; srcw = w_v; dstw = wF16_v; }
        int o = i / 192, rem = i - o * 192;
        int c = rem / 3, k = rem - 3 * c;
        int Kp = ((c >> 3) & 1) * 96 + (c >> 4) * 24 + (c & 7) * 3 + k;
        dstw[o * 192 + Kp] = (_Float16)srcw[i];
    }
}

// ---------------------------------------------------------------------------
// Bilinear tap -> paired-load form (round-6 verified). 2 pair-loads + 4 FMAs
// per (channel, tap); edge validity folded into pair weights.
// ---------------------------------------------------------------------------
__device__ __forceinline__ void tap_setup(
    float fi, float fj, float dy, float dx, float m, float kyo, float kxo,
    int& b0, int& b1, float& wA0, float& wB0, float& wA1, float& wB1)
{
    float py = fi + kyo + dy;
    float px = fj + kxo + dx;
    float y0f = floorf(py), x0f = floorf(px);
    float wy = py - y0f, wx = px - x0f;
    int y0 = (int)y0f, x0 = (int)x0f;
    int y1 = y0 + 1, x1 = x0 + 1;
    bool vy0 = (y0 >= 0) && (y0 < H_);
    bool vy1 = (y1 >= 0) && (y1 < H_);
    bool vx0 = (x0 >= 0) && (x0 < W_);
    bool vx1 = (x1 >= 0) && (x1 < W_);
    int y0c = min(max(y0, 0), H_ - 1), y1c = min(max(y1, 0), H_ - 1);
    int xb = min(max(x0, 0), W_ - 2);
    int s0 = min(max(x0 - xb, 0), 1);      // v00 = pair[s0]
    int s1 = min(max(x1 - xb, 0), 1);      // v01 = pair[s1]
    float wy1 = 1.f - wy, wx1 = 1.f - wx;
    float w00 = (vy0 && vx0) ? wy1 * wx1 * m : 0.f;
    float w01 = (vy0 && vx1) ? wy1 * wx  * m : 0.f;
    float w10 = (vy1 && vx0) ? wy  * wx1 * m : 0.f;
    float w11 = (vy1 && vx1) ? wy  * wx  * m : 0.f;
    wA0 = (s0 ? 0.f : w00) + (s1 ? 0.f : w01);
    wB0 = (s0 ? w00 : 0.f) + (s1 ? w01 : 0.f);
    wA1 = (s0 ? 0.f : w10) + (s1 ? 0.f : w11);
    wB1 = (s0 ? w10 : 0.f) + (s1 ? w11 : 0.f);
    b0 = y0c * W_ + xb;
    b1 = y1c * W_ + xb;
}

// XCD-aware swizzle: one image (n) = 4 MB = exactly one XCD's L2. Blocks go
// to XCDs round-robin by blockIdx%8, so n = bid&7 pins image k to XCD k and
// kills the 4.3x cross-XCD HBM re-fetch.
#define SWIZZLE_NP()                        \
    int bid = blockIdx.x;                   \
    int n   = bid & 7;                      \
    int m   = bid >> 3;      /* 0..255 in-image tile */ \
    int pix = m * 64 + lane;                \
    int j = pix & (W_ - 1);                 \
    int i = pix >> 7;

// Gather one g-group (8 channels x 3 taps) into t8[3] (half8 each).
#define GATHER_G(BASE, G, T8)                                                 \
    {                                                                         \
        _Pragma("unroll")                                                     \
        for (int cl = 0; cl < 8; ++cl) {                                      \
            const float* s = (BASE) + ((G) * 8 + cl) * HW_;                   \
            _Pragma("unroll")                                                 \
            for (int k = 0; k < 3; ++k) {                                     \
                f2 p0 = *(const f2*)(s + b0[k]);                              \
                f2 p1 = *(const f2*)(s + b1[k]);                              \
                float v = fmaf(wA0[k], p0.x, fmaf(wB0[k], p0.y,               \
                          fmaf(wA1[k], p1.x, wB1[k] * p1.y)));                \
                int t = cl * 3 + k;                                           \
                (T8)[t >> 3][t & 7] = (_Float16)v;                            \
            }                                                                 \
        }                                                                     \
    }

// One MFMA round: 3 MFMAs x 4 tiles over K = r*96 .. r*96+95.
#define MROUND(A0_, A1_, A2_)                                                 \
    {                                                                         \
        _Pragma("unroll")                                                     \
        for (int T = 0; T < 4; ++T) {                                         \
            const _Float16* bp = &valT[T * 16 + col][(lane >> 4) << 3];       \
            floatx4 acc = accT[T];                                            \
            acc = __builtin_amdgcn_mfma_f32_16x16x32_f16(A0_, *((const half8*)(bp +  0)), acc, 0, 0, 0); \
            acc = __builtin_amdgcn_mfma_f32_16x16x32_f16(A1_, *((const half8*)(bp + 32)), acc, 0, 0, 0); \
            acc = __builtin_amdgcn_mfma_f32_16x16x32_f16(A2_, *((const half8*)(bp + 64)), acc, 0, 0, 0); \
            accT[T] = acc;                                                    \
        }                                                                     \
    }

// ---------------------------------------------------------------------------
// Fused horizontal pass. Round-8: split-K (2x96) MFMA so valT = 13.3 KB and
// block LDS = 18.4 KB (red) -> 8 blocks/CU resident, grid 2048 = one clean
// generation (was 6-resident -> ragged 1536+512, avg occupancy 40%).
// ---------------------------------------------------------------------------
__global__ __launch_bounds__(256, 8) void deform_h_kernel(
    const float* __restrict__ x, const float* __restrict__ wOffAll,
    const float* __restrict__ b_off_h, const float* __restrict__ b_mask_h,
    const float* __restrict__ b_off_v, const float* __restrict__ b_mask_v,
    const _Float16* __restrict__ wF16, const float* __restrict__ bias,
    float* __restrict__ off_v, float* __restrict__ mask_v,
    float* __restrict__ out)
{
    __shared__ __align__(16) char smem[18432];
    float (*red)[18][64] = reinterpret_cast<float(*)[18][64]>(smem);
    _Float16 (*valT)[104] = reinterpret_cast<_Float16(*)[104]>(smem);

    int lane = threadIdx.x & 63;
    int wv   = threadIdx.x >> 6;
    int c0 = __builtin_amdgcn_readfirstlane(wv << 4);   // SGPR slice base

    SWIZZLE_NP();

    // ---- offs prologue: 5-pt stencil over this wave's 16 channels ----
    float a[18];
    #pragma unroll
    for (int o = 0; o < 18; ++o) a[o] = 0.f;

    const float* xs = x + (size_t)n * C_ * HW_ + (size_t)c0 * HW_;
    for (int cc = 0; cc < 16; ++cc) {
        const float* s = xs + cc * HW_;
        float xc = s[pix];
        float xl = (j > 0)      ? s[pix - 1]  : 0.f;
        float xr = (j < W_ - 1) ? s[pix + 1]  : 0.f;
        float xu = (i > 0)      ? s[pix - W_] : 0.f;
        float xd = (i < H_ - 1) ? s[pix + W_] : 0.f;
        const float* wc = wOffAll + (c0 + cc) * 56;   // uniform -> s_load
        #pragma unroll
        for (int o = 0; o < 6; ++o) {
            a[o]   = fmaf(xl, wc[3*o],    fmaf(xc, wc[3*o+1],    fmaf(xr, wc[3*o+2],    a[o])));
            a[9+o] = fmaf(xu, wc[27+3*o], fmaf(xc, wc[27+3*o+1], fmaf(xd, wc[27+3*o+2], a[9+o])));
        }
        #pragma unroll
        for (int o = 0; o < 3; ++o) {
            a[6+o]  = fmaf(xl, wc[18+3*o], fmaf(xc, wc[18+3*o+1], fmaf(xr, wc[18+3*o+2], a[6+o])));
            a[15+o] = fmaf(xu, wc[45+3*o], fmaf(xc, wc[45+3*o+1], fmaf(xd, wc[45+3*o+2], a[15+o])));
        }
    }

    // ---- cross-wave reduce: h-set -> LDS (consumed below), v-set -> ws ----
    #pragma unroll
    for (int o = 0; o < 18; ++o) red[wv][o][lane] = a[o];
    __syncthreads();

    for (int v = threadIdx.x; v < 18 * 64; v += 256) {
        int idx = v >> 6;
        int px  = v & 63;
        float sum = red[0][idx][px] + red[1][idx][px]
                  + red[2][idx][px] + red[3][idx][px];
        int pixg = m * 64 + px;
        if (idx < 6) {
            red[0][idx][px] = sum + b_off_h[idx];    // (idx,px) has unique owner
        } else if (idx < 9) {
            red[0][idx][px] = 1.f / (1.f + __expf(-(sum + b_mask_h[idx - 6])));
        } else if (idx < 15) {
            // re-read by v-kernel from L2: plain store (round-1 nt was a loss)
            off_v[((size_t)n * 6 + (idx - 9)) * HW_ + pixg] = sum + b_off_v[idx - 9];
        } else {
            mask_v[((size_t)n * 3 + (idx - 15)) * HW_ + pixg] =
                1.f / (1.f + __expf(-(sum + b_mask_v[idx - 15])));
        }
    }
    __syncthreads();

    float dyk[3], dxk[3], mk[3];
    #pragma unroll
    for (int k = 0; k < 3; ++k) {
        dyk[k] = red[0][2*k    ][lane];
        dxk[k] = red[0][2*k + 1][lane];
        mk [k] = red[0][6 + k  ][lane];
    }
    __syncthreads();   // all reads of red done before valT overwrites smem

    // ---- tap setup (horizontal: kyo=0, kxo=k-1) ----
    int b0[3], b1[3];
    float wA0[3], wB0[3], wA1[3], wB1[3];
    #pragma unroll
    for (int k = 0; k < 3; ++k)
        tap_setup((float)i, (float)j, dyk[k], dxk[k], mk[k], 0.f, (float)(k - 1),
                  b0[k], b1[k], wA0[k], wB0[k], wA1[k], wB1[k]);

    // ---- split-K pipeline: gather g0 -> LDS -> MFMA(K0..95) overlapping
    //      gather g1 -> LDS -> MFMA(K96..191) ----
    half8 t8a[3], t8b[3];
    GATHER_G(xs, 0, t8a)
    #pragma unroll
    for (int w = 0; w < 3; ++w)
        *((half8*)&valT[lane][wv * 24 + w * 8]) = t8a[w];

    GATHER_G(xs, 1, t8b)          // loads issue before the barrier
    __syncthreads();

    const _Float16* wpA = wF16 + (size_t)(c0 + (lane & 15)) * 192 + ((lane >> 4) << 3);
    int col  = lane & 15;
    floatx4 accT[4];
    #pragma unroll
    for (int T = 0; T < 4; ++T) accT[T] = floatx4{0.f, 0.f, 0.f, 0.f};

    {
        half8 A0 = *((const half8*)(wpA +  0));
        half8 A1 = *((const half8*)(wpA + 32));
        half8 A2 = *((const half8*)(wpA + 64));
        MROUND(A0, A1, A2)
    }
    __syncthreads();   // round-0 reads done
    #pragma unroll
    for (int w = 0; w < 3; ++w)
        *((half8*)&valT[lane][wv * 24 + w * 8]) = t8b[w];
    __syncthreads();
    {
        half8 A3 = *((const half8*)(wpA +  96));
        half8 A4 = *((const half8*)(wpA + 128));
        half8 A5 = *((const half8*)(wpA + 160));
        MROUND(A3, A4, A5)
    }

    int orow = c0 + ((lane >> 4) << 2);
    floatx4 bv = *((const floatx4*)&bias[orow]);
    float* ob = out + ((size_t)n * C_ + orow) * HW_ + m * 64 + col;
    #pragma unroll
    for (int T = 0; T < 4; ++T) {
        ob[T * 16 + (size_t)0 * HW_] = accT[T][0] + bv[0];
        ob[T * 16 + (size_t)1 * HW_] = accT[T][1] + bv[1];
        ob[T * 16 + (size_t)2 * HW_] = accT[T][2] + bv[2];
        ob[T * 16 + (size_t)3 * HW_] = accT[T][3] + bv[3];
    }
}

// ---------------------------------------------------------------------------
// Vertical pass: deformable (K,1) conv on x_h; offsets/masks precomputed.
// Same swizzle (x_h layout identical to x). Split-K as in h-kernel:
// LDS 13.3 KB -> 8 blocks/CU. Final out is never re-read -> nt-stores.
// ---------------------------------------------------------------------------
__global__ __launch_bounds__(256, 8) void deform_v_kernel(
    const float* __restrict__ src, const float* __restrict__ off,
    const float* __restrict__ mask, const _Float16* __restrict__ wF16,
    const float* __restrict__ bias, float* __restrict__ out)
{
    __shared__ __align__(16) _Float16 valT[64][104];

    int lane = threadIdx.x & 63;
    int wv   = threadIdx.x >> 6;
    int c0 = __builtin_amdgcn_readfirstlane(wv << 4);

    SWIZZLE_NP();

    int b0[3], b1[3];
    float wA0[3], wB0[3], wA1[3], wB1[3];
    #pragma unroll
    for (int k = 0; k < 3; ++k) {
        float dy = off[(((size_t)n * 3 + k) * 2 + 0) * HW_ + pix];
        float dx = off[(((size_t)n * 3 + k) * 2 + 1) * HW_ + pix];
        float m_ = mask[((size_t)n * 3 + k) * HW_ + pix];
        tap_setup((float)i, (float)j, dy, dx, m_, (float)(k - 1), 0.f,
                  b0[k], b1[k], wA0[k], wB0[k], wA1[k], wB1[k]);
    }

    const float* sb = src + (size_t)n * C_ * HW_ + (size_t)c0 * HW_;

    half8 t8a[3], t8b[3];
    GATHER_G(sb, 0, t8a)
    #pragma unroll
    for (int w = 0; w < 3; ++w)
        *((half8*)&valT[lane][wv * 24 + w * 8]) = t8a[w];

    GATHER_G(sb, 1, t8b)
    __syncthreads();

    const _Float16* wpA = wF16 + (size_t)(c0 + (lane & 15)) * 192 + ((lane >> 4) << 3);
    int col  = lane & 15;
    floatx4 accT[4];
    #pragma unroll
    for (int T = 0; T < 4; ++T) accT[T] = floatx4{0.f, 0.f, 0.f, 0.f};

    {
        half8 A0 = *((const half8*)(wpA +  0));
        half8 A1 = *((const half8*)(wpA + 32));
        half8 A2 = *((const half8*)(wpA + 64));
        MROUND(A0, A1, A2)
    }
    __syncthreads();
    #pragma unroll
    for (int w = 0; w < 3; ++w)
        *((half8*)&valT[lane][wv * 24 + w * 8]) = t8b[w];
    __syncthreads();
    {
        half8 A3 = *((const half8*)(wpA +  96));
        half8 A4 = *((const half8*)(wpA + 128));
        half8 A5 = *((const half8*)(wpA + 160));
        MROUND(A3, A4, A5)
    }

    int orow = c0 + ((lane >> 4) << 2);
    floatx4 bv = *((const floatx4*)&bias[orow]);
    float* ob = out + ((size_t)n * C_ + orow) * HW_ + m * 64 + col;
    #pragma unroll
    for (int T = 0; T < 4; ++T) {
        __builtin_nontemporal_store(accT[T][0] + bv[0], &ob[T * 16 + (size_t)0 * HW_]);
        __builtin_nontemporal_store(accT[T][1] + bv[1], &ob[T * 16 + (size_t)1 * HW_]);
        __builtin_nontemporal_store(accT[T][2] + bv[2], &ob[T * 16 + (size_t)2 * HW_]);
        __builtin_nontemporal_store(accT[T][3] + bv[3], &ob[T * 16 + (size_t)3 * HW_]);
    }
}

// ---------------------------------------------------------------------------
extern "C" void kernel_launch(void* const* d_in, const int* in_sizes, int n_in,
                              void* d_out, int out_size, void* d_ws, size_t ws_size,
                              hipStream_t stream)
{
    const float* x        = (const float*)d_in[0];
    const float* w_off_h  = (const float*)d_in[1];
    const float* b_off_h  = (const float*)d_in[2];
    const float* w_mask_h = (const float*)d_in[3];
    const float* b_mask_h = (const float*)d_in[4];
    const float* w_off_v  = (const float*)d_in[5];
    const float* b_off_v  = (const float*)d_in[6];
    const float* w_mask_v = (const float*)d_in[7];
    const float* b_mask_v = (const float*)d_in[8];
    const float* w_h      = (const float*)d_in[9];
    const float* b_h      = (const float*)d_in[10];
    const float* w_v      = (const float*)d_in[11];
    const float* b_v      = (const float*)d_in[12];

    float* ws      = (float*)d_ws;
    float* off_v   = ws;                    // 786432
    float* mask_v  = off_v  + 786432;       // 393216
    float* x_h     = mask_v + 393216;       // 8388608
    float* wOffAll = x_h    + 8388608;      // 3584
    _Float16* wF16_h = (_Float16*)(wOffAll + 3584);  // 12288 halfs
    _Float16* wF16_v = wF16_h + 12288;               // 12288 halfs

    prep_kernel<<<110, 256, 0, stream>>>(
        w_off_h, w_mask_h, w_off_v, w_mask_v, w_h, w_v,
        wOffAll, wF16_h, wF16_v);

    dim3 grid(NPIX / 64), block(256);
    deform_h_kernel<<<grid, block, 0, stream>>>(
        x, wOffAll, b_off_h, b_mask_h, b_off_v, b_mask_v,
        wF16_h, b_h, off_v, mask_v, x_h);

    deform_v_kernel<<<grid, block, 0, stream>>>(
        x_h, off_v, mask_v, wF16_v, b_v, (float*)d_out);
}

// Round 3
// 201.939 us; speedup vs baseline: 1.1498x; 1.1168x over previous
//
#include <hip/hip_runtime.h>

#define C_ 64
#define H_ 128
#define W_ 128
#define B_ 8
#define HW_ (H_*W_)
#define NPIX (B_*HW_)

typedef _Float16 half8 __attribute__((ext_vector_type(8)));
typedef float floatx4 __attribute__((ext_vector_type(4)));
// 4-B-aligned pair for bilinear corner loads (x0,x0+1 adjacent in memory).
struct f2 { float x, y; };

// ---------------------------------------------------------------------------
// Prep: pack offset/mask weights into contiguous per-channel rows
// wOffAll[c][56] and cast deform weights to f16.
// wF16_h: round-2 split-K permutation  K'(c,k) = g*96 + wv*24 + cl*3 + k.
// wF16_v: PLAIN cast — the NHWC v-kernel contracts over K' = 3c+k, which is
// exactly the native flattening of w_v[o][c][k].
// ---------------------------------------------------------------------------
__global__ __launch_bounds__(256) void prep_kernel(
    const float* __restrict__ w_off_h, const float* __restrict__ w_mask_h,
    const float* __restrict__ w_off_v, const float* __restrict__ w_mask_v,
    const float* __restrict__ w_h, const float* __restrict__ w_v,
    float* __restrict__ wOffAll, _Float16* __restrict__ wF16_h,
    _Float16* __restrict__ wF16_v)
{
    int gid = blockIdx.x * 256 + threadIdx.x;
    if (gid < 64 * 56) {
        int c = gid / 56, idx = gid - 56 * c;
        float v = 0.f;
        if (idx < 18)      v = w_off_h [((idx      ) / 3) * 192 + c * 3 + (idx      ) % 3];
        else if (idx < 27) v = w_mask_h[((idx - 18) / 3) * 192 + c * 3 + (idx - 18) % 3];
        else if (idx < 45) v = w_off_v [((idx - 27) / 3) * 192 + c * 3 + (idx - 27) % 3];
        else if (idx < 54) v = w_mask_v[((idx - 45) / 3) * 192 + c * 3 + (idx - 45) % 3];
        wOffAll[c * 56 + idx] = v;
    } else if (gid < 3584 + 24576) {
        int i = gid - 3584;
        if (i < 12288) {
            int o = i / 192, rem = i - o * 192;
            int c = rem / 3, k = rem - 3 * c;
            int Kp = ((c >> 3) & 1) * 96 + (c >> 4) * 24 + (c & 7) * 3 + k;
            wF16_h[o * 192 + Kp] = (_Float16)w_h[i];
        } else {
            i -= 12288;
            wF16_v[i] = (_Float16)w_v[i];
        }
    }
}

// ---------------------------------------------------------------------------
// Bilinear tap -> paired-load form (round-6 verified). 2 pair-loads + 4 FMAs
// per (channel, tap); edge validity folded into pair weights. (h-kernel only)
// ---------------------------------------------------------------------------
__device__ __forceinline__ void tap_setup(
    float fi, float fj, float dy, float dx, float m, float kyo, float kxo,
    int& b0, int& b1, float& wA0, float& wB0, float& wA1, float& wB1)
{
    float py = fi + kyo + dy;
    float px = fj + kxo + dx;
    float y0f = floorf(py), x0f = floorf(px);
    float wy = py - y0f, wx = px - x0f;
    int y0 = (int)y0f, x0 = (int)x0f;
    int y1 = y0 + 1, x1 = x0 + 1;
    bool vy0 = (y0 >= 0) && (y0 < H_);
    bool vy1 = (y1 >= 0) && (y1 < H_);
    bool vx0 = (x0 >= 0) && (x0 < W_);
    bool vx1 = (x1 >= 0) && (x1 < W_);
    int y0c = min(max(y0, 0), H_ - 1), y1c = min(max(y1, 0), H_ - 1);
    int xb = min(max(x0, 0), W_ - 2);
    int s0 = min(max(x0 - xb, 0), 1);      // v00 = pair[s0]
    int s1 = min(max(x1 - xb, 0), 1);      // v01 = pair[s1]
    float wy1 = 1.f - wy, wx1 = 1.f - wx;
    float w00 = (vy0 && vx0) ? wy1 * wx1 * m : 0.f;
    float w01 = (vy0 && vx1) ? wy1 * wx  * m : 0.f;
    float w10 = (vy1 && vx0) ? wy  * wx1 * m : 0.f;
    float w11 = (vy1 && vx1) ? wy  * wx  * m : 0.f;
    wA0 = (s0 ? 0.f : w00) + (s1 ? 0.f : w01);
    wB0 = (s0 ? w00 : 0.f) + (s1 ? w01 : 0.f);
    wA1 = (s0 ? 0.f : w10) + (s1 ? 0.f : w11);
    wB1 = (s0 ? w10 : 0.f) + (s1 ? w11 : 0.f);
    b0 = y0c * W_ + xb;
    b1 = y1c * W_ + xb;
}

// XCD-aware swizzle: one image (n) pinned to XCD n (bid&7).
#define SWIZZLE_NP()                        \
    int bid = blockIdx.x;                   \
    int n   = bid & 7;                      \
    int m   = bid >> 3;      /* 0..255 in-image tile */ \
    int pix = m * 64 + lane;                \
    int j = pix & (W_ - 1);                 \
    int i = pix >> 7;

// Gather one g-group (8 channels x 3 taps) into t8[3] (half8 each).
#define GATHER_G(BASE, G, T8)                                                 \
    {                                                                         \
        _Pragma("unroll")                                                     \
        for (int cl = 0; cl < 8; ++cl) {                                      \
            const float* s = (BASE) + ((G) * 8 + cl) * HW_;                   \
            _Pragma("unroll")                                                 \
            for (int k = 0; k < 3; ++k) {                                     \
                f2 p0 = *(const f2*)(s + b0[k]);                              \
                f2 p1 = *(const f2*)(s + b1[k]);                              \
                float v = fmaf(wA0[k], p0.x, fmaf(wB0[k], p0.y,               \
                          fmaf(wA1[k], p1.x, wB1[k] * p1.y)));                \
                int t = cl * 3 + k;                                           \
                (T8)[t >> 3][t & 7] = (_Float16)v;                            \
            }                                                                 \
        }                                                                     \
    }

// One MFMA round: 3 MFMAs x 4 tiles over K = r*96 .. r*96+95 (h-kernel).
#define MROUND(A0_, A1_, A2_)                                                 \
    {                                                                         \
        _Pragma("unroll")                                                     \
        for (int T = 0; T < 4; ++T) {                                         \
            const _Float16* bp = &valT[T * 16 + col][(lane >> 4) << 3];       \
            floatx4 acc = accT[T];                                            \
            acc = __builtin_amdgcn_mfma_f32_16x16x32_f16(A0_, *((const half8*)(bp +  0)), acc, 0, 0, 0); \
            acc = __builtin_amdgcn_mfma_f32_16x16x32_f16(A1_, *((const half8*)(bp + 32)), acc, 0, 0, 0); \
            acc = __builtin_amdgcn_mfma_f32_16x16x32_f16(A2_, *((const half8*)(bp + 64)), acc, 0, 0, 0); \
            accT[T] = acc;                                                    \
        }                                                                     \
    }

// ---------------------------------------------------------------------------
// Fused horizontal pass (round-2 structure). Round-3 change: x_h is written
// in NHWC f32 ([n][pix][c]) so the v-kernel can gather coalesced. Epilogue is
// one float4 store per tile (numerics identical to round-2).
// ---------------------------------------------------------------------------
__global__ __launch_bounds__(256, 8) void deform_h_kernel(
    const float* __restrict__ x, const float* __restrict__ wOffAll,
    const float* __restrict__ b_off_h, const float* __restrict__ b_mask_h,
    const float* __restrict__ b_off_v, const float* __restrict__ b_mask_v,
    const _Float16* __restrict__ wF16, const float* __restrict__ bias,
    float* __restrict__ off_v, float* __restrict__ mask_v,
    float* __restrict__ x_hT)
{
    __shared__ __align__(16) char smem[18432];
    float (*red)[18][64] = reinterpret_cast<float(*)[18][64]>(smem);
    _Float16 (*valT)[104] = reinterpret_cast<_Float16(*)[104]>(smem);

    int lane = threadIdx.x & 63;
    int wv   = threadIdx.x >> 6;
    int c0 = __builtin_amdgcn_readfirstlane(wv << 4);   // SGPR slice base

    SWIZZLE_NP();

    // ---- offs prologue: 5-pt stencil over this wave's 16 channels ----
    float a[18];
    #pragma unroll
    for (int o = 0; o < 18; ++o) a[o] = 0.f;

    const float* xs = x + (size_t)n * C_ * HW_ + (size_t)c0 * HW_;
    for (int cc = 0; cc < 16; ++cc) {
        const float* s = xs + cc * HW_;
        float xc = s[pix];
        float xl = (j > 0)      ? s[pix - 1]  : 0.f;
        float xr = (j < W_ - 1) ? s[pix + 1]  : 0.f;
        float xu = (i > 0)      ? s[pix - W_] : 0.f;
        float xd = (i < H_ - 1) ? s[pix + W_] : 0.f;
        const float* wc = wOffAll + (c0 + cc) * 56;   // uniform -> s_load
        #pragma unroll
        for (int o = 0; o < 6; ++o) {
            a[o]   = fmaf(xl, wc[3*o],    fmaf(xc, wc[3*o+1],    fmaf(xr, wc[3*o+2],    a[o])));
            a[9+o] = fmaf(xu, wc[27+3*o], fmaf(xc, wc[27+3*o+1], fmaf(xd, wc[27+3*o+2], a[9+o])));
        }
        #pragma unroll
        for (int o = 0; o < 3; ++o) {
            a[6+o]  = fmaf(xl, wc[18+3*o], fmaf(xc, wc[18+3*o+1], fmaf(xr, wc[18+3*o+2], a[6+o])));
            a[15+o] = fmaf(xu, wc[45+3*o], fmaf(xc, wc[45+3*o+1], fmaf(xd, wc[45+3*o+2], a[15+o])));
        }
    }

    // ---- cross-wave reduce: h-set -> LDS (consumed below), v-set -> ws ----
    #pragma unroll
    for (int o = 0; o < 18; ++o) red[wv][o][lane] = a[o];
    __syncthreads();

    for (int v = threadIdx.x; v < 18 * 64; v += 256) {
        int idx = v >> 6;
        int px  = v & 63;
        float sum = red[0][idx][px] + red[1][idx][px]
                  + red[2][idx][px] + red[3][idx][px];
        int pixg = m * 64 + px;
        if (idx < 6) {
            red[0][idx][px] = sum + b_off_h[idx];    // (idx,px) has unique owner
        } else if (idx < 9) {
            red[0][idx][px] = 1.f / (1.f + __expf(-(sum + b_mask_h[idx - 6])));
        } else if (idx < 15) {
            off_v[((size_t)n * 6 + (idx - 9)) * HW_ + pixg] = sum + b_off_v[idx - 9];
        } else {
            mask_v[((size_t)n * 3 + (idx - 15)) * HW_ + pixg] =
                1.f / (1.f + __expf(-(sum + b_mask_v[idx - 15])));
        }
    }
    __syncthreads();

    float dyk[3], dxk[3], mk[3];
    #pragma unroll
    for (int k = 0; k < 3; ++k) {
        dyk[k] = red[0][2*k    ][lane];
        dxk[k] = red[0][2*k + 1][lane];
        mk [k] = red[0][6 + k  ][lane];
    }
    __syncthreads();   // all reads of red done before valT overwrites smem

    // ---- tap setup (horizontal: kyo=0, kxo=k-1) ----
    int b0[3], b1[3];
    float wA0[3], wB0[3], wA1[3], wB1[3];
    #pragma unroll
    for (int k = 0; k < 3; ++k)
        tap_setup((float)i, (float)j, dyk[k], dxk[k], mk[k], 0.f, (float)(k - 1),
                  b0[k], b1[k], wA0[k], wB0[k], wA1[k], wB1[k]);

    // ---- split-K pipeline ----
    half8 t8a[3], t8b[3];
    GATHER_G(xs, 0, t8a)
    #pragma unroll
    for (int w = 0; w < 3; ++w)
        *((half8*)&valT[lane][wv * 24 + w * 8]) = t8a[w];

    GATHER_G(xs, 1, t8b)          // loads issue before the barrier
    __syncthreads();

    const _Float16* wpA = wF16 + (size_t)(c0 + (lane & 15)) * 192 + ((lane >> 4) << 3);
    int col  = lane & 15;
    floatx4 accT[4];
    #pragma unroll
    for (int T = 0; T < 4; ++T) accT[T] = floatx4{0.f, 0.f, 0.f, 0.f};

    {
        half8 A0 = *((const half8*)(wpA +  0));
        half8 A1 = *((const half8*)(wpA + 32));
        half8 A2 = *((const half8*)(wpA + 64));
        MROUND(A0, A1, A2)
    }
    __syncthreads();   // round-0 reads done
    #pragma unroll
    for (int w = 0; w < 3; ++w)
        *((half8*)&valT[lane][wv * 24 + w * 8]) = t8b[w];
    __syncthreads();
    {
        half8 A3 = *((const half8*)(wpA +  96));
        half8 A4 = *((const half8*)(wpA + 128));
        half8 A5 = *((const half8*)(wpA + 160));
        MROUND(A3, A4, A5)
    }

    // ---- epilogue: NHWC f32 store, one float4 per tile ----
    int orow = c0 + ((lane >> 4) << 2);
    floatx4 bv = *((const floatx4*)&bias[orow]);
    float* hb = x_hT + ((size_t)n * HW_ + (size_t)m * 64) * 64 + orow;
    #pragma unroll
    for (int T = 0; T < 4; ++T) {
        floatx4 o;
        o[0] = accT[T][0] + bv[0];
        o[1] = accT[T][1] + bv[1];
        o[2] = accT[T][2] + bv[2];
        o[3] = accT[T][3] + bv[3];
        *((floatx4*)(hb + (size_t)(T * 16 + col) * 64)) = o;
    }
}

// ---------------------------------------------------------------------------
// Vertical pass, round-3 NHWC redesign. Source x_hT is [n][pix][64] f32, so
// each bilinear corner is 64 consecutive floats: one coalesced 256-B
// wave-load with a wave-uniform address (lane = channel). Tap coords/weights
// are per-pixel scalars computed once by threads 0..191 into LDS.
// Per wave: 8 pixels/half x 12 coalesced loads, bilinear with broadcast
// weights, f16 into valT[pix][K'=3c+k], then the verified MFMA layout.
// ---------------------------------------------------------------------------
__global__ __launch_bounds__(256, 8) void deform_v_kernel(
    const float* __restrict__ srcT, const float* __restrict__ off,
    const float* __restrict__ mask, const _Float16* __restrict__ wF16,
    const float* __restrict__ bias, float* __restrict__ out)
{
    // valT: [32][200] halfs = 12800 B   | tapI: 192*16 = 3072 B
    // tapW: 192*16 = 3072 B             | total 18944 B -> 8 blocks/CU
    __shared__ __align__(16) char smem[18944];
    _Float16 (*valT)[200] = reinterpret_cast<_Float16(*)[200]>(smem);
    int4*   tapI = reinterpret_cast<int4*>(smem + 12800);
    floatx4* tapW = reinterpret_cast<floatx4*>(smem + 12800 + 3072);

    int lane = threadIdx.x & 63;
    int wv   = threadIdx.x >> 6;
    int c0 = __builtin_amdgcn_readfirstlane(wv << 4);

    int bid = blockIdx.x;
    int n   = bid & 7;
    int m   = bid >> 3;

    // ---- tap setup: thread t<192 handles (pixel p = t/3, tap k = t%3) ----
    int t = threadIdx.x;
    if (t < 192) {
        int p = t / 3, k = t - 3 * p;
        int pixp = m * 64 + p;
        float dy = off[(((size_t)n * 3 + k) * 2 + 0) * HW_ + pixp];
        float dx = off[(((size_t)n * 3 + k) * 2 + 1) * HW_ + pixp];
        float mm = mask[((size_t)n * 3 + k) * HW_ + pixp];
        float fi = (float)(pixp >> 7), fj = (float)(pixp & (W_ - 1));
        float py = fi + (float)(k - 1) + dy;   // vertical: kyo = k-1, kxo = 0
        float px = fj + dx;
        float y0f = floorf(py), x0f = floorf(px);
        float wy = py - y0f, wx = px - x0f;
        int y0 = (int)y0f, x0 = (int)x0f;
        int y1 = y0 + 1, x1 = x0 + 1;
        bool vy0 = (y0 >= 0) && (y0 < H_);
        bool vy1 = (y1 >= 0) && (y1 < H_);
        bool vx0 = (x0 >= 0) && (x0 < W_);
        bool vx1 = (x1 >= 0) && (x1 < W_);
        int y0c = min(max(y0, 0), H_ - 1), y1c = min(max(y1, 0), H_ - 1);
        int x0c = min(max(x0, 0), W_ - 1), x1c = min(max(x1, 0), W_ - 1);
        float wy1 = 1.f - wy, wx1 = 1.f - wx;
        floatx4 w;
        w[0] = (vy0 && vx0) ? wy1 * wx1 * mm : 0.f;
        w[1] = (vy0 && vx1) ? wy1 * wx  * mm : 0.f;
        w[2] = (vy1 && vx0) ? wy  * wx1 * mm : 0.f;
        w[3] = (vy1 && vx1) ? wy  * wx  * mm : 0.f;
        int4 e;
        e.x = (y0c * W_ + x0c) * 64;
        e.y = (y0c * W_ + x1c) * 64;
        e.z = (y1c * W_ + x0c) * 64;
        e.w = (y1c * W_ + x1c) * 64;
        tapI[t] = e;
        tapW[t] = w;
    }
    __syncthreads();

    const float* sT = srcT + (size_t)n * (HW_ * 64);
    int col = lane & 15;
    floatx4 accT[4];
    #pragma unroll
    for (int T = 0; T < 4; ++T) accT[T] = floatx4{0.f, 0.f, 0.f, 0.f};

    #pragma unroll
    for (int hf = 0; hf < 2; ++hf) {
        // ---- gather: this wave's 8 pixels, 12 coalesced corner loads each ----
        #pragma unroll
        for (int q = 0; q < 8; ++q) {
            int r = wv * 8 + q;            // valT row
            int p = hf * 32 + r;           // pixel within block
            #pragma unroll
            for (int k = 0; k < 3; ++k) {
                int4 e = tapI[p * 3 + k];
                floatx4 w = tapW[p * 3 + k];
                float v00 = sT[e.x + lane];
                float v01 = sT[e.y + lane];
                float v10 = sT[e.z + lane];
                float v11 = sT[e.w + lane];
                float v = fmaf(w[0], v00, fmaf(w[1], v01,
                          fmaf(w[2], v10, w[3] * v11)));
                valT[r][3 * lane + k] = (_Float16)v;   // K' = 3c+k
            }
        }
        __syncthreads();

        // ---- MFMA: tiles 2*hf, 2*hf+1 over full K=192 ----
        const _Float16* wpA = wF16 + (size_t)(c0 + (lane & 15)) * 192 + ((lane >> 4) << 3);
        half8 A0 = *((const half8*)(wpA +   0));
        half8 A1 = *((const half8*)(wpA +  32));
        half8 A2 = *((const half8*)(wpA +  64));
        half8 A3 = *((const half8*)(wpA +  96));
        half8 A4 = *((const half8*)(wpA + 128));
        half8 A5 = *((const half8*)(wpA + 160));
        #pragma unroll
        for (int tt = 0; tt < 2; ++tt) {
            int T = hf * 2 + tt;
            const _Float16* bp = &valT[tt * 16 + col][(lane >> 4) << 3];
            floatx4 acc = accT[T];
            acc = __builtin_amdgcn_mfma_f32_16x16x32_f16(A0, *((const half8*)(bp +   0)), acc, 0, 0, 0);
            acc = __builtin_amdgcn_mfma_f32_16x16x32_f16(A1, *((const half8*)(bp +  32)), acc, 0, 0, 0);
            acc = __builtin_amdgcn_mfma_f32_16x16x32_f16(A2, *((const half8*)(bp +  64)), acc, 0, 0, 0);
            acc = __builtin_amdgcn_mfma_f32_16x16x32_f16(A3, *((const half8*)(bp +  96)), acc, 0, 0, 0);
            acc = __builtin_amdgcn_mfma_f32_16x16x32_f16(A4, *((const half8*)(bp + 128)), acc, 0, 0, 0);
            acc = __builtin_amdgcn_mfma_f32_16x16x32_f16(A5, *((const half8*)(bp + 160)), acc, 0, 0, 0);
            accT[T] = acc;
        }
        if (hf == 0) __syncthreads();   // reads done before half-1 overwrites valT
    }

    // ---- epilogue: out is NCHW f32 (reference layout), nt-stores ----
    int orow = c0 + ((lane >> 4) << 2);
    floatx4 bv = *((const floatx4*)&bias[orow]);
    float* ob = out + ((size_t)n * C_ + orow) * HW_ + m * 64 + col;
    #pragma unroll
    for (int T = 0; T < 4; ++T) {
        __builtin_nontemporal_store(accT[T][0] + bv[0], &ob[T * 16 + (size_t)0 * HW_]);
        __builtin_nontemporal_store(accT[T][1] + bv[1], &ob[T * 16 + (size_t)1 * HW_]);
        __builtin_nontemporal_store(accT[T][2] + bv[2], &ob[T * 16 + (size_t)2 * HW_]);
        __builtin_nontemporal_store(accT[T][3] + bv[3], &ob[T * 16 + (size_t)3 * HW_]);
    }
}

// ---------------------------------------------------------------------------
extern "C" void kernel_launch(void* const* d_in, const int* in_sizes, int n_in,
                              void* d_out, int out_size, void* d_ws, size_t ws_size,
                              hipStream_t stream)
{
    const float* x        = (const float*)d_in[0];
    const float* w_off_h  = (const float*)d_in[1];
    const float* b_off_h  = (const float*)d_in[2];
    const float* w_mask_h = (const float*)d_in[3];
    const float* b_mask_h = (const float*)d_in[4];
    const float* w_off_v  = (const float*)d_in[5];
    const float* b_off_v  = (const float*)d_in[6];
    const float* w_mask_v = (const float*)d_in[7];
    const float* b_mask_v = (const float*)d_in[8];
    const float* w_h      = (const float*)d_in[9];
    const float* b_h      = (const float*)d_in[10];
    const float* w_v      = (const float*)d_in[11];
    const float* b_v      = (const float*)d_in[12];

    float* ws      = (float*)d_ws;
    float* off_v   = ws;                    // 786432
    float* mask_v  = off_v  + 786432;       // 393216
    float* x_hT    = mask_v + 393216;       // 8388608 (NHWC f32 [n][pix][c])
    float* wOffAll = x_hT   + 8388608;      // 3584
    _Float16* wF16_h = (_Float16*)(wOffAll + 3584);  // 12288 halfs
    _Float16* wF16_v = wF16_h + 12288;               // 12288 halfs

    prep_kernel<<<110, 256, 0, stream>>>(
        w_off_h, w_mask_h, w_off_v, w_mask_v, w_h, w_v,
        wOffAll, wF16_h, wF16_v);

    dim3 grid(NPIX / 64), block(256);
    deform_h_kernel<<<grid, block, 0, stream>>>(
        x, wOffAll, b_off_h, b_mask_h, b_off_v, b_mask_v,
        wF16_h, b_h, off_v, mask_v, x_hT);

    deform_v_kernel<<<grid, block, 0, stream>>>(
        x_hT, off_v, mask_v, wF16_v, b_v, (float*)d_out);
}

// Round 4
// 195.490 us; speedup vs baseline: 1.1877x; 1.0330x over previous
//
#include <hip/hip_runtime.h>

#define C_ 64
#define H_ 128
#define W_ 128
#define B_ 8
#define HW_ (H_*W_)
#define NPIX (B_*HW_)

typedef _Float16 half8 __attribute__((ext_vector_type(8)));
typedef _Float16 half4 __attribute__((ext_vector_type(4)));
typedef float floatx4 __attribute__((ext_vector_type(4)));

// ---------------------------------------------------------------------------
// Prep: pack offset/mask weights into contiguous per-channel rows
// wOffAll[c][56]; cast deform weights to f16 with PLAIN (o, 3c+k) flatten —
// both NHWC gather kernels contract over K' = 3c+k, the native flattening.
// ---------------------------------------------------------------------------
__global__ __launch_bounds__(256) void prep_kernel(
    const float* __restrict__ w_off_h, const float* __restrict__ w_mask_h,
    const float* __restrict__ w_off_v, const float* __restrict__ w_mask_v,
    const float* __restrict__ w_h, const float* __restrict__ w_v,
    float* __restrict__ wOffAll, _Float16* __restrict__ wF16_h,
    _Float16* __restrict__ wF16_v)
{
    int gid = blockIdx.x * 256 + threadIdx.x;
    if (gid < 64 * 56) {
        int c = gid / 56, idx = gid - 56 * c;
        float v = 0.f;
        if (idx < 18)      v = w_off_h [((idx      ) / 3) * 192 + c * 3 + (idx      ) % 3];
        else if (idx < 27) v = w_mask_h[((idx - 18) / 3) * 192 + c * 3 + (idx - 18) % 3];
        else if (idx < 45) v = w_off_v [((idx - 27) / 3) * 192 + c * 3 + (idx - 27) % 3];
        else if (idx < 54) v = w_mask_v[((idx - 45) / 3) * 192 + c * 3 + (idx - 45) % 3];
        wOffAll[c * 56 + idx] = v;
    } else if (gid < 3584 + 24576) {
        int i = gid - 3584;
        if (i < 12288) wF16_h[i] = (_Float16)w_h[i];
        else           wF16_v[i - 12288] = (_Float16)w_v[i - 12288];
    }
}

// ---------------------------------------------------------------------------
// Transpose x: NCHW f32 -> NHWC f16 ([n][pix][c]) so deform_h's gathers are
// coalesced wave-uniform 128-B loads. LDS-staged; [64][66] pad makes the
// transposed read conflict-free ((33*lane)%32 = lane).
// ---------------------------------------------------------------------------
__global__ __launch_bounds__(256, 8) void transpose_kernel(
    const float* __restrict__ x, _Float16* __restrict__ xT)
{
    __shared__ _Float16 tile[64][66];
    int lane = threadIdx.x & 63;
    int wv   = threadIdx.x >> 6;
    int bid = blockIdx.x;
    int n = bid & 7;          // XCD-pinned, same mapping as consumers
    int m = bid >> 3;
    const float* xs = x + (size_t)n * C_ * HW_ + (size_t)m * 64;
    #pragma unroll
    for (int cc = 0; cc < 16; ++cc) {
        int c = wv * 16 + cc;
        tile[c][lane] = (_Float16)xs[(size_t)c * HW_ + lane];
    }
    __syncthreads();
    _Float16* xd = xT + ((size_t)n * HW_ + (size_t)m * 64) * 64;
    #pragma unroll
    for (int pp = 0; pp < 16; ++pp) {
        int p = wv * 16 + pp;
        xd[(size_t)p * 64 + lane] = tile[lane][p];
    }
}

// XCD-aware swizzle: one image (n) pinned to XCD n (bid&7).
#define SWIZZLE_NP()                        \
    int bid = blockIdx.x;                   \
    int n   = bid & 7;                      \
    int m   = bid >> 3;      /* 0..255 in-image tile */ \
    int pix = m * 64 + lane;                \
    int j = pix & (W_ - 1);                 \
    int i = pix >> 7;

// Per-(pixel,tap) 4-corner setup -> LDS tapI/tapW (threads t < 192).
// KYO/KXO are expressions in k (tap displacement on y or x).
#define TAP_SETUP_192(OFFP, MASKP, KYO, KXO)                                  \
    {                                                                         \
        int t = threadIdx.x;                                                  \
        if (t < 192) {                                                        \
            int p = t / 3, k = t - 3 * p;                                     \
            int pixp = m * 64 + p;                                            \
            float dy = (OFFP##_DY);                                           \
            float dx = (OFFP##_DX);                                           \
            float mm = (MASKP);                                               \
            float fi = (float)(pixp >> 7), fj = (float)(pixp & (W_ - 1));     \
            float py = fi + (float)(KYO) + dy;                                \
            float px = fj + (float)(KXO) + dx;                                \
            float y0f = floorf(py), x0f = floorf(px);                         \
            float wy = py - y0f, wx = px - x0f;                               \
            int y0 = (int)y0f, x0 = (int)x0f;                                 \
            int y1 = y0 + 1, x1 = x0 + 1;                                     \
            bool vy0 = (y0 >= 0) && (y0 < H_);                                \
            bool vy1 = (y1 >= 0) && (y1 < H_);                                \
            bool vx0 = (x0 >= 0) && (x0 < W_);                                \
            bool vx1 = (x1 >= 0) && (x1 < W_);                                \
            int y0c = min(max(y0, 0), H_ - 1), y1c = min(max(y1, 0), H_ - 1); \
            int x0c = min(max(x0, 0), W_ - 1), x1c = min(max(x1, 0), W_ - 1); \
            float wy1 = 1.f - wy, wx1 = 1.f - wx;                             \
            floatx4 w;                                                        \
            w[0] = (vy0 && vx0) ? wy1 * wx1 * mm : 0.f;                       \
            w[1] = (vy0 && vx1) ? wy1 * wx  * mm : 0.f;                       \
            w[2] = (vy1 && vx0) ? wy  * wx1 * mm : 0.f;                       \
            w[3] = (vy1 && vx1) ? wy  * wx  * mm : 0.f;                       \
            int4 e;                                                           \
            e.x = (y0c * W_ + x0c) * 64;                                      \
            e.y = (y0c * W_ + x1c) * 64;                                      \
            e.z = (y1c * W_ + x0c) * 64;                                      \
            e.w = (y1c * W_ + x1c) * 64;                                      \
            tapI[t] = e;                                                      \
            tapW[t] = w;                                                      \
        }                                                                     \
    }

// NHWC gather + MFMA over two 32-pixel halves (round-3 verified structure).
// sT: f16 NHWC image base. Writes OUT via the EPILOGUE macro at the end.
#define GATHER_MFMA_BODY(ST)                                                  \
    int col = lane & 15;                                                      \
    floatx4 accT[4];                                                          \
    _Pragma("unroll")                                                         \
    for (int T = 0; T < 4; ++T) accT[T] = floatx4{0.f, 0.f, 0.f, 0.f};        \
    _Pragma("unroll")                                                         \
    for (int hf = 0; hf < 2; ++hf) {                                          \
        _Pragma("unroll")                                                     \
        for (int q = 0; q < 8; ++q) {                                         \
            int r = wv * 8 + q;                                               \
            int p = hf * 32 + r;                                              \
            _Pragma("unroll")                                                 \
            for (int k = 0; k < 3; ++k) {                                     \
                int4 e = tapI[p * 3 + k];                                     \
                floatx4 w = tapW[p * 3 + k];                                  \
                float v00 = (float)(ST)[e.x + lane];                          \
                float v01 = (float)(ST)[e.y + lane];                          \
                float v10 = (float)(ST)[e.z + lane];                          \
                float v11 = (float)(ST)[e.w + lane];                          \
                float v = fmaf(w[0], v00, fmaf(w[1], v01,                     \
                          fmaf(w[2], v10, w[3] * v11)));                      \
                valT[r][3 * lane + k] = (_Float16)v;                          \
            }                                                                 \
        }                                                                     \
        __syncthreads();                                                      \
        const _Float16* wpA = wF16 + (size_t)(c0 + (lane & 15)) * 192         \
                            + ((lane >> 4) << 3);                             \
        half8 A0 = *((const half8*)(wpA +   0));                              \
        half8 A1 = *((const half8*)(wpA +  32));                              \
        half8 A2 = *((const half8*)(wpA +  64));                              \
        half8 A3 = *((const half8*)(wpA +  96));                              \
        half8 A4 = *((const half8*)(wpA + 128));                              \
        half8 A5 = *((const half8*)(wpA + 160));                              \
        _Pragma("unroll")                                                     \
        for (int tt = 0; tt < 2; ++tt) {                                      \
            int T = hf * 2 + tt;                                              \
            const _Float16* bp = &valT[tt * 16 + col][(lane >> 4) << 3];      \
            floatx4 acc = accT[T];                                            \
            acc = __builtin_amdgcn_mfma_f32_16x16x32_f16(A0, *((const half8*)(bp +   0)), acc, 0, 0, 0); \
            acc = __builtin_amdgcn_mfma_f32_16x16x32_f16(A1, *((const half8*)(bp +  32)), acc, 0, 0, 0); \
            acc = __builtin_amdgcn_mfma_f32_16x16x32_f16(A2, *((const half8*)(bp +  64)), acc, 0, 0, 0); \
            acc = __builtin_amdgcn_mfma_f32_16x16x32_f16(A3, *((const half8*)(bp +  96)), acc, 0, 0, 0); \
            acc = __builtin_amdgcn_mfma_f32_16x16x32_f16(A4, *((const half8*)(bp + 128)), acc, 0, 0, 0); \
            acc = __builtin_amdgcn_mfma_f32_16x16x32_f16(A5, *((const half8*)(bp + 160)), acc, 0, 0, 0); \
            accT[T] = acc;                                                    \
        }                                                                     \
        if (hf == 0) __syncthreads();                                         \
    }

// ---------------------------------------------------------------------------
// Fused horizontal pass, round-4: NHWC gathers from xT (f16), same structure
// as the round-3 v-kernel. Prologue (offsets/masks from x, NCHW, coalesced)
// unchanged. Output x_hT is NHWC f16.
// smem phases: [prologue red 18432] -> [tap t<192: reads red[0] bytes<2304,
// writes tapI/tapW @12800+] -> [valT 0..12800 | tapI/tapW persist].
// ---------------------------------------------------------------------------
__global__ __launch_bounds__(256, 8) void deform_h_kernel(
    const float* __restrict__ x, const _Float16* __restrict__ xT,
    const float* __restrict__ wOffAll,
    const float* __restrict__ b_off_h, const float* __restrict__ b_mask_h,
    const float* __restrict__ b_off_v, const float* __restrict__ b_mask_v,
    const _Float16* __restrict__ wF16, const float* __restrict__ bias,
    float* __restrict__ off_v, float* __restrict__ mask_v,
    _Float16* __restrict__ x_hT)
{
    __shared__ __align__(16) char smem[18944];
    float (*red)[18][64] = reinterpret_cast<float(*)[18][64]>(smem);
    float (*red0)[64]    = reinterpret_cast<float(*)[64]>(smem);
    _Float16 (*valT)[200] = reinterpret_cast<_Float16(*)[200]>(smem);  // 32 rows
    int4*    tapI = reinterpret_cast<int4*>(smem + 12800);
    floatx4* tapW = reinterpret_cast<floatx4*>(smem + 12800 + 3072);

    int lane = threadIdx.x & 63;
    int wv   = threadIdx.x >> 6;
    int c0 = __builtin_amdgcn_readfirstlane(wv << 4);   // SGPR slice base

    SWIZZLE_NP();

    // ---- offs prologue: 5-pt stencil over this wave's 16 channels ----
    float a[18];
    #pragma unroll
    for (int o = 0; o < 18; ++o) a[o] = 0.f;

    const float* xs = x + (size_t)n * C_ * HW_ + (size_t)c0 * HW_;
    for (int cc = 0; cc < 16; ++cc) {
        const float* s = xs + cc * HW_;
        float xc = s[pix];
        float xl = (j > 0)      ? s[pix - 1]  : 0.f;
        float xr = (j < W_ - 1) ? s[pix + 1]  : 0.f;
        float xu = (i > 0)      ? s[pix - W_] : 0.f;
        float xd = (i < H_ - 1) ? s[pix + W_] : 0.f;
        const float* wc = wOffAll + (c0 + cc) * 56;   // uniform -> s_load
        #pragma unroll
        for (int o = 0; o < 6; ++o) {
            a[o]   = fmaf(xl, wc[3*o],    fmaf(xc, wc[3*o+1],    fmaf(xr, wc[3*o+2],    a[o])));
            a[9+o] = fmaf(xu, wc[27+3*o], fmaf(xc, wc[27+3*o+1], fmaf(xd, wc[27+3*o+2], a[9+o])));
        }
        #pragma unroll
        for (int o = 0; o < 3; ++o) {
            a[6+o]  = fmaf(xl, wc[18+3*o], fmaf(xc, wc[18+3*o+1], fmaf(xr, wc[18+3*o+2], a[6+o])));
            a[15+o] = fmaf(xu, wc[45+3*o], fmaf(xc, wc[45+3*o+1], fmaf(xd, wc[45+3*o+2], a[15+o])));
        }
    }

    // ---- cross-wave reduce: h-set -> red[0], v-set -> ws ----
    #pragma unroll
    for (int o = 0; o < 18; ++o) red[wv][o][lane] = a[o];
    __syncthreads();

    for (int v = threadIdx.x; v < 18 * 64; v += 256) {
        int idx = v >> 6;
        int px  = v & 63;
        float sum = red[0][idx][px] + red[1][idx][px]
                  + red[2][idx][px] + red[3][idx][px];
        int pixg = m * 64 + px;
        if (idx < 6) {
            red[0][idx][px] = sum + b_off_h[idx];    // (idx,px) has unique owner
        } else if (idx < 9) {
            red[0][idx][px] = 1.f / (1.f + __expf(-(sum + b_mask_h[idx - 6])));
        } else if (idx < 15) {
            off_v[((size_t)n * 6 + (idx - 9)) * HW_ + pixg] = sum + b_off_v[idx - 9];
        } else {
            mask_v[((size_t)n * 3 + (idx - 15)) * HW_ + pixg] =
                1.f / (1.f + __expf(-(sum + b_mask_v[idx - 15])));
        }
    }
    __syncthreads();

    // ---- tap setup (horizontal: kyo=0, kxo=k-1) from red[0] ----
#define H_DY red0[2*k    ][p]
#define H_DX red0[2*k + 1][p]
    TAP_SETUP_192(H, red0[6 + k][p], 0, (k - 1))
#undef H_DY
#undef H_DX
    __syncthreads();   // tap reads of red0 done before valT overwrites

    const _Float16* sT = xT + (size_t)n * (HW_ * 64);
    GATHER_MFMA_BODY(sT)

    // ---- epilogue: NHWC f16 store, one half4 per tile ----
    int orow = c0 + ((lane >> 4) << 2);
    floatx4 bv = *((const floatx4*)&bias[orow]);
    _Float16* hb = x_hT + ((size_t)n * HW_ + (size_t)m * 64) * 64 + orow;
    #pragma unroll
    for (int T = 0; T < 4; ++T) {
        half4 o;
        o[0] = (_Float16)(accT[T][0] + bv[0]);
        o[1] = (_Float16)(accT[T][1] + bv[1]);
        o[2] = (_Float16)(accT[T][2] + bv[2]);
        o[3] = (_Float16)(accT[T][3] + bv[3]);
        *((half4*)(hb + (size_t)(T * 16 + col) * 64)) = o;
    }
}

// ---------------------------------------------------------------------------
// Vertical pass (round-3 NHWC structure, src now f16): offsets/masks
// precomputed; gathers are coalesced 128-B wave loads from x_hT.
// ---------------------------------------------------------------------------
__global__ __launch_bounds__(256, 8) void deform_v_kernel(
    const _Float16* __restrict__ srcT, const float* __restrict__ off,
    const float* __restrict__ mask, const _Float16* __restrict__ wF16,
    const float* __restrict__ bias, float* __restrict__ out)
{
    __shared__ __align__(16) char smem[18944];
    _Float16 (*valT)[200] = reinterpret_cast<_Float16(*)[200]>(smem);
    int4*    tapI = reinterpret_cast<int4*>(smem + 12800);
    floatx4* tapW = reinterpret_cast<floatx4*>(smem + 12800 + 3072);

    int lane = threadIdx.x & 63;
    int wv   = threadIdx.x >> 6;
    int c0 = __builtin_amdgcn_readfirstlane(wv << 4);

    int bid = blockIdx.x;
    int n   = bid & 7;
    int m   = bid >> 3;

    // ---- tap setup (vertical: kyo=k-1, kxo=0) from off/mask in ws ----
#define V_DY off[(((size_t)n * 3 + k) * 2 + 0) * HW_ + pixp]
#define V_DX off[(((size_t)n * 3 + k) * 2 + 1) * HW_ + pixp]
    TAP_SETUP_192(V, mask[((size_t)n * 3 + k) * HW_ + pixp], (k - 1), 0)
#undef V_DY
#undef V_DX
    __syncthreads();

    const _Float16* sT = srcT + (size_t)n * (HW_ * 64);
    GATHER_MFMA_BODY(sT)

    // ---- epilogue: out is NCHW f32 (reference layout), nt-stores ----
    int orow = c0 + ((lane >> 4) << 2);
    floatx4 bv = *((const floatx4*)&bias[orow]);
    float* ob = out + ((size_t)n * C_ + orow) * HW_ + m * 64 + col;
    #pragma unroll
    for (int T = 0; T < 4; ++T) {
        __builtin_nontemporal_store(accT[T][0] + bv[0], &ob[T * 16 + (size_t)0 * HW_]);
        __builtin_nontemporal_store(accT[T][1] + bv[1], &ob[T * 16 + (size_t)1 * HW_]);
        __builtin_nontemporal_store(accT[T][2] + bv[2], &ob[T * 16 + (size_t)2 * HW_]);
        __builtin_nontemporal_store(accT[T][3] + bv[3], &ob[T * 16 + (size_t)3 * HW_]);
    }
}

// ---------------------------------------------------------------------------
extern "C" void kernel_launch(void* const* d_in, const int* in_sizes, int n_in,
                              void* d_out, int out_size, void* d_ws, size_t ws_size,
                              hipStream_t stream)
{
    const float* x        = (const float*)d_in[0];
    const float* w_off_h  = (const float*)d_in[1];
    const float* b_off_h  = (const float*)d_in[2];
    const float* w_mask_h = (const float*)d_in[3];
    const float* b_mask_h = (const float*)d_in[4];
    const float* w_off_v  = (const float*)d_in[5];
    const float* b_off_v  = (const float*)d_in[6];
    const float* w_mask_v = (const float*)d_in[7];
    const float* b_mask_v = (const float*)d_in[8];
    const float* w_h      = (const float*)d_in[9];
    const float* b_h      = (const float*)d_in[10];
    const float* w_v      = (const float*)d_in[11];
    const float* b_v      = (const float*)d_in[12];

    // ws: f32 region then f16 region; total ~38.3 MB (within known-good).
    float* ws      = (float*)d_ws;
    float* off_v   = ws;                    // 786432 f32
    float* mask_v  = off_v  + 786432;       // 393216 f32
    float* wOffAll = mask_v + 393216;       // 3584 f32
    _Float16* xT     = (_Float16*)(wOffAll + 3584);   // 8388608 f16 (x NHWC)
    _Float16* x_hT   = xT + 8388608;                  // 8388608 f16 (x_h NHWC)
    _Float16* wF16_h = x_hT + 8388608;                // 12288 f16
    _Float16* wF16_v = wF16_h + 12288;                // 12288 f16

    prep_kernel<<<110, 256, 0, stream>>>(
        w_off_h, w_mask_h, w_off_v, w_mask_v, w_h, w_v,
        wOffAll, wF16_h, wF16_v);

    dim3 grid(NPIX / 64), block(256);
    transpose_kernel<<<grid, block, 0, stream>>>(x, xT);

    deform_h_kernel<<<grid, block, 0, stream>>>(
        x, xT, wOffAll, b_off_h, b_mask_h, b_off_v, b_mask_v,
        wF16_h, b_h, off_v, mask_v, x_hT);

    deform_v_kernel<<<grid, block, 0, stream>>>(
        x_hT, off_v, mask_v, wF16_v, b_v, (float*)d_out);
}

// Round 6
// 190.322 us; speedup vs baseline: 1.2200x; 1.0272x over previous
//
#include <hip/hip_runtime.h>

#define C_ 64
#define H_ 128
#define W_ 128
#define B_ 8
#define HW_ (H_*W_)
#define NPIX (B_*HW_)

typedef _Float16 half8 __attribute__((ext_vector_type(8)));
typedef _Float16 half4 __attribute__((ext_vector_type(4)));
typedef float floatx4 __attribute__((ext_vector_type(4)));

// ---------------------------------------------------------------------------
// Prep: pack offset/mask weights into contiguous per-channel rows
// wOffAll[c][56]; cast deform weights to f16 with K' = k*64 + c layout
// (matches the conflict-free valT write pattern valT[r][k*64+lane]).
// ---------------------------------------------------------------------------
__global__ __launch_bounds__(256) void prep_kernel(
    const float* __restrict__ w_off_h, const float* __restrict__ w_mask_h,
    const float* __restrict__ w_off_v, const float* __restrict__ w_mask_v,
    const float* __restrict__ w_h, const float* __restrict__ w_v,
    float* __restrict__ wOffAll, _Float16* __restrict__ wF16_h,
    _Float16* __restrict__ wF16_v)
{
    int gid = blockIdx.x * 256 + threadIdx.x;
    if (gid < 64 * 56) {
        int c = gid / 56, idx = gid - 56 * c;
        float v = 0.f;
        if (idx < 18)      v = w_off_h [((idx      ) / 3) * 192 + c * 3 + (idx      ) % 3];
        else if (idx < 27) v = w_mask_h[((idx - 18) / 3) * 192 + c * 3 + (idx - 18) % 3];
        else if (idx < 45) v = w_off_v [((idx - 27) / 3) * 192 + c * 3 + (idx - 27) % 3];
        else if (idx < 54) v = w_mask_v[((idx - 45) / 3) * 192 + c * 3 + (idx - 45) % 3];
        wOffAll[c * 56 + idx] = v;
    } else if (gid < 3584 + 24576) {
        int i = gid - 3584;
        if (i < 12288) {
            int o = i / 192, rem = i - o * 192;
            int c = rem / 3, k = rem - 3 * c;
            wF16_h[o * 192 + k * 64 + c] = (_Float16)w_h[i];
        } else {
            i -= 12288;
            int o = i / 192, rem = i - o * 192;
            int c = rem / 3, k = rem - 3 * c;
            wF16_v[o * 192 + k * 64 + c] = (_Float16)w_v[i];
        }
    }
}

// ---------------------------------------------------------------------------
// Transpose x: NCHW f32 -> NHWC f16 ([n][pix][c]) so deform_h's gathers are
// coalesced wave-uniform 128-B loads. LDS-staged; [64][66] pad makes the
// transposed read conflict-free.
// ---------------------------------------------------------------------------
__global__ __launch_bounds__(256, 8) void transpose_kernel(
    const float* __restrict__ x, _Float16* __restrict__ xT)
{
    __shared__ _Float16 tile[64][66];
    int lane = threadIdx.x & 63;
    int wv   = threadIdx.x >> 6;
    int bid = blockIdx.x;
    int n = bid & 7;          // XCD-pinned, same mapping as consumers
    int m = bid >> 3;
    const float* xs = x + (size_t)n * C_ * HW_ + (size_t)m * 64;
    #pragma unroll
    for (int cc = 0; cc < 16; ++cc) {
        int c = wv * 16 + cc;
        tile[c][lane] = (_Float16)xs[(size_t)c * HW_ + lane];
    }
    __syncthreads();
    _Float16* xd = xT + ((size_t)n * HW_ + (size_t)m * 64) * 64;
    #pragma unroll
    for (int pp = 0; pp < 16; ++pp) {
        int p = wv * 16 + pp;
        xd[(size_t)p * 64 + lane] = tile[lane][p];
    }
}

// XCD-aware swizzle: one image (n) pinned to XCD n (bid&7).
#define SWIZZLE_NP()                        \
    int bid = blockIdx.x;                   \
    int n   = bid & 7;                      \
    int m   = bid >> 3;      /* 0..255 in-image tile */ \
    int pix = m * 64 + lane;                \
    int j = pix & (W_ - 1);                 \
    int i = pix >> 7;

// Per-(pixel,tap) setup -> LDS (threads t < 192).
// Round-6 fix (round-5 NaN): the 2x2 load tile base (yb,xb) is CLAMPED into
// the image (yb in [0,H-2], xb in [0,W-2]) so all 4 reads hit real pixels
// (finite, deterministic). Each corner's weight is ROUTED to its relative
// slot (y_c - yb, x_c - xb) in {0,1}^2; invalid corners have zero weight, so
// slot collisions are additive no-ops. Numerics identical to round-4.
#define TAP_SETUP_192(OFFP, MASKP, KYO, KXO)                                  \
    {                                                                         \
        int t = threadIdx.x;                                                  \
        if (t < 192) {                                                        \
            int p = t / 3, k = t - 3 * p;                                     \
            int pixp = m * 64 + p;                                            \
            float dy = (OFFP##_DY);                                           \
            float dx = (OFFP##_DX);                                           \
            float mm = (MASKP);                                               \
            float fi = (float)(pixp >> 7), fj = (float)(pixp & (W_ - 1));     \
            float py = fi + (float)(KYO) + dy;                                \
            float px = fj + (float)(KXO) + dx;                                \
            float y0f = floorf(py), x0f = floorf(px);                         \
            float wy = py - y0f, wx = px - x0f;                               \
            int y0 = (int)y0f, x0 = (int)x0f;                                 \
            int y1 = y0 + 1, x1 = x0 + 1;                                     \
            bool vy0 = (y0 >= 0) && (y0 < H_);                                \
            bool vy1 = (y1 >= 0) && (y1 < H_);                                \
            bool vx0 = (x0 >= 0) && (x0 < W_);                                \
            bool vx1 = (x1 >= 0) && (x1 < W_);                                \
            float wy1 = 1.f - wy, wx1 = 1.f - wx;                             \
            float w00 = (vy0 && vx0) ? wy1 * wx1 * mm : 0.f;                  \
            float w01 = (vy0 && vx1) ? wy1 * wx  * mm : 0.f;                  \
            float w10 = (vy1 && vx0) ? wy  * wx1 * mm : 0.f;                  \
            float w11 = (vy1 && vx1) ? wy  * wx  * mm : 0.f;                  \
            int y0c = min(max(y0, 0), H_ - 1), y1c = min(max(y1, 0), H_ - 1); \
            int x0c = min(max(x0, 0), W_ - 1), x1c = min(max(x1, 0), W_ - 1); \
            int yb = min(max(y0, 0), H_ - 2),  xb = min(max(x0, 0), W_ - 2);  \
            int r0 = y0c - yb, r1 = y1c - yb;   /* in {0,1} */                \
            int cA = x0c - xb, cB = x1c - xb;   /* in {0,1} */                \
            floatx4 w;                                                        \
            w[0] = ((r0==0)&&(cA==0)?w00:0.f) + ((r0==0)&&(cB==0)?w01:0.f)    \
                 + ((r1==0)&&(cA==0)?w10:0.f) + ((r1==0)&&(cB==0)?w11:0.f);   \
            w[1] = ((r0==0)&&(cA==1)?w00:0.f) + ((r0==0)&&(cB==1)?w01:0.f)    \
                 + ((r1==0)&&(cA==1)?w10:0.f) + ((r1==0)&&(cB==1)?w11:0.f);   \
            w[2] = ((r0==1)&&(cA==0)?w00:0.f) + ((r0==1)&&(cB==0)?w01:0.f)    \
                 + ((r1==1)&&(cA==0)?w10:0.f) + ((r1==1)&&(cB==0)?w11:0.f);   \
            w[3] = ((r0==1)&&(cA==1)?w00:0.f) + ((r0==1)&&(cB==1)?w01:0.f)    \
                 + ((r1==1)&&(cA==1)?w10:0.f) + ((r1==1)&&(cB==1)?w11:0.f);   \
            tapI[t] = (yb * W_ + xb) * 64;                                    \
            tapW[t] = w;                                                      \
        }                                                                     \
    }

// NHWC gather + MFMA over two 32-pixel halves. Wave-uniform base in SGPR via
// readfirstlane (loads become s_base + lane*2 + imm), conflict-free valT
// writes (K' = k*64 + lane -> contiguous 128-B wave store). All reads
// in-image (base clamped, weights routed).
#define GATHER_MFMA_BODY(ST)                                                  \
    int col = lane & 15;                                                      \
    floatx4 accT[4];                                                          \
    _Pragma("unroll")                                                         \
    for (int T = 0; T < 4; ++T) accT[T] = floatx4{0.f, 0.f, 0.f, 0.f};        \
    _Pragma("unroll")                                                         \
    for (int hf = 0; hf < 2; ++hf) {                                          \
        _Pragma("unroll")                                                     \
        for (int q = 0; q < 8; ++q) {                                         \
            int r = wv * 8 + q;                                               \
            int p = hf * 32 + r;                                              \
            _Pragma("unroll")                                                 \
            for (int k = 0; k < 3; ++k) {                                     \
                int ex = __builtin_amdgcn_readfirstlane(tapI[p * 3 + k]);     \
                floatx4 w = tapW[p * 3 + k];                                  \
                const _Float16* cb = (ST) + ex;                               \
                float v00 = (float)cb[lane];                                  \
                float v01 = (float)cb[lane + 64];                             \
                float v10 = (float)cb[lane + 64 * W_];                        \
                float v11 = (float)cb[lane + 64 * W_ + 64];                   \
                float v = fmaf(w[0], v00, fmaf(w[1], v01,                     \
                          fmaf(w[2], v10, w[3] * v11)));                      \
                valT[r][k * 64 + lane] = (_Float16)v;                         \
            }                                                                 \
        }                                                                     \
        __syncthreads();                                                      \
        const _Float16* wpA = wF16 + (size_t)(c0 + (lane & 15)) * 192         \
                            + ((lane >> 4) << 3);                             \
        half8 A0 = *((const half8*)(wpA +   0));                              \
        half8 A1 = *((const half8*)(wpA +  32));                              \
        half8 A2 = *((const half8*)(wpA +  64));                              \
        half8 A3 = *((const half8*)(wpA +  96));                              \
        half8 A4 = *((const half8*)(wpA + 128));                              \
        half8 A5 = *((const half8*)(wpA + 160));                              \
        _Pragma("unroll")                                                     \
        for (int tt = 0; tt < 2; ++tt) {                                      \
            int T = hf * 2 + tt;                                              \
            const _Float16* bp = &valT[tt * 16 + col][(lane >> 4) << 3];      \
            floatx4 acc = accT[T];                                            \
            acc = __builtin_amdgcn_mfma_f32_16x16x32_f16(A0, *((const half8*)(bp +   0)), acc, 0, 0, 0); \
            acc = __builtin_amdgcn_mfma_f32_16x16x32_f16(A1, *((const half8*)(bp +  32)), acc, 0, 0, 0); \
            acc = __builtin_amdgcn_mfma_f32_16x16x32_f16(A2, *((const half8*)(bp +  64)), acc, 0, 0, 0); \
            acc = __builtin_amdgcn_mfma_f32_16x16x32_f16(A3, *((const half8*)(bp +  96)), acc, 0, 0, 0); \
            acc = __builtin_amdgcn_mfma_f32_16x16x32_f16(A4, *((const half8*)(bp + 128)), acc, 0, 0, 0); \
            acc = __builtin_amdgcn_mfma_f32_16x16x32_f16(A5, *((const half8*)(bp + 160)), acc, 0, 0, 0); \
            accT[T] = acc;                                                    \
        }                                                                     \
        if (hf == 0) __syncthreads();                                         \
    }

// ---------------------------------------------------------------------------
// Fused horizontal pass. Prologue (offsets/masks from x, NCHW) unchanged.
// smem: prologue red[4][18][64] (18432 B) -> tap_setup reads red0 (first
// 2304 B), writes tapI@12800/tapW@13568 -> gather valT 0..12800.
// ---------------------------------------------------------------------------
__global__ __launch_bounds__(256, 8) void deform_h_kernel(
    const float* __restrict__ x, const _Float16* __restrict__ xT,
    const float* __restrict__ wOffAll,
    const float* __restrict__ b_off_h, const float* __restrict__ b_mask_h,
    const float* __restrict__ b_off_v, const float* __restrict__ b_mask_v,
    const _Float16* __restrict__ wF16, const float* __restrict__ bias,
    float* __restrict__ off_v, float* __restrict__ mask_v,
    _Float16* __restrict__ x_hT)
{
    __shared__ __align__(16) char smem[18432];
    float (*red)[18][64] = reinterpret_cast<float(*)[18][64]>(smem);
    float (*red0)[64]    = reinterpret_cast<float(*)[64]>(smem);
    _Float16 (*valT)[200] = reinterpret_cast<_Float16(*)[200]>(smem);  // 32 rows
    int*     tapI = reinterpret_cast<int*>(smem + 12800);     // 768 B
    floatx4* tapW = reinterpret_cast<floatx4*>(smem + 13568); // 3072 B

    int lane = threadIdx.x & 63;
    int wv   = threadIdx.x >> 6;
    int c0 = __builtin_amdgcn_readfirstlane(wv << 4);   // SGPR slice base

    SWIZZLE_NP();

    // ---- offs prologue: 5-pt stencil over this wave's 16 channels ----
    float a[18];
    #pragma unroll
    for (int o = 0; o < 18; ++o) a[o] = 0.f;

    const float* xs = x + (size_t)n * C_ * HW_ + (size_t)c0 * HW_;
    for (int cc = 0; cc < 16; ++cc) {
        const float* s = xs + cc * HW_;
        float xc = s[pix];
        float xl = (j > 0)      ? s[pix - 1]  : 0.f;
        float xr = (j < W_ - 1) ? s[pix + 1]  : 0.f;
        float xu = (i > 0)      ? s[pix - W_] : 0.f;
        float xd = (i < H_ - 1) ? s[pix + W_] : 0.f;
        const float* wc = wOffAll + (c0 + cc) * 56;   // uniform -> s_load
        #pragma unroll
        for (int o = 0; o < 6; ++o) {
            a[o]   = fmaf(xl, wc[3*o],    fmaf(xc, wc[3*o+1],    fmaf(xr, wc[3*o+2],    a[o])));
            a[9+o] = fmaf(xu, wc[27+3*o], fmaf(xc, wc[27+3*o+1], fmaf(xd, wc[27+3*o+2], a[9+o])));
        }
        #pragma unroll
        for (int o = 0; o < 3; ++o) {
            a[6+o]  = fmaf(xl, wc[18+3*o], fmaf(xc, wc[18+3*o+1], fmaf(xr, wc[18+3*o+2], a[6+o])));
            a[15+o] = fmaf(xu, wc[45+3*o], fmaf(xc, wc[45+3*o+1], fmaf(xd, wc[45+3*o+2], a[15+o])));
        }
    }

    // ---- cross-wave reduce: h-set -> red0, v-set -> ws ----
    #pragma unroll
    for (int o = 0; o < 18; ++o) red[wv][o][lane] = a[o];
    __syncthreads();

    for (int v = threadIdx.x; v < 18 * 64; v += 256) {
        int idx = v >> 6;
        int px  = v & 63;
        float sum = red[0][idx][px] + red[1][idx][px]
                  + red[2][idx][px] + red[3][idx][px];
        int pixg = m * 64 + px;
        if (idx < 6) {
            red[0][idx][px] = sum + b_off_h[idx];    // (idx,px) has unique owner
        } else if (idx < 9) {
            red[0][idx][px] = 1.f / (1.f + __expf(-(sum + b_mask_h[idx - 6])));
        } else if (idx < 15) {
            off_v[((size_t)n * 6 + (idx - 9)) * HW_ + pixg] = sum + b_off_v[idx - 9];
        } else {
            mask_v[((size_t)n * 3 + (idx - 15)) * HW_ + pixg] =
                1.f / (1.f + __expf(-(sum + b_mask_v[idx - 15])));
        }
    }
    __syncthreads();

    // ---- tap setup (horizontal: kyo=0, kxo=k-1) from red0 ----
#define H_DY red0[2*k    ][p]
#define H_DX red0[2*k + 1][p]
    TAP_SETUP_192(H, red0[6 + k][p], 0, (k - 1))
#undef H_DY
#undef H_DX
    __syncthreads();   // tap reads of red0 done before valT overwrites

    const _Float16* sT = xT + (size_t)n * (HW_ * 64);
    GATHER_MFMA_BODY(sT)

    // ---- epilogue: NHWC f16 store, one half4 per tile ----
    int orow = c0 + ((lane >> 4) << 2);
    floatx4 bv = *((const floatx4*)&bias[orow]);
    _Float16* hb = x_hT + ((size_t)n * HW_ + (size_t)m * 64) * 64 + orow;
    #pragma unroll
    for (int T = 0; T < 4; ++T) {
        half4 o;
        o[0] = (_Float16)(accT[T][0] + bv[0]);
        o[1] = (_Float16)(accT[T][1] + bv[1]);
        o[2] = (_Float16)(accT[T][2] + bv[2]);
        o[3] = (_Float16)(accT[T][3] + bv[3]);
        *((half4*)(hb + (size_t)(T * 16 + col) * 64)) = o;
    }
}

// ---------------------------------------------------------------------------
// Vertical pass: offsets/masks precomputed; coalesced NHWC gathers from x_hT.
// ---------------------------------------------------------------------------
__global__ __launch_bounds__(256, 8) void deform_v_kernel(
    const _Float16* __restrict__ srcT, const float* __restrict__ off,
    const float* __restrict__ mask, const _Float16* __restrict__ wF16,
    const float* __restrict__ bias, float* __restrict__ out)
{
    __shared__ __align__(16) char smem[16640];
    _Float16 (*valT)[200] = reinterpret_cast<_Float16(*)[200]>(smem);
    int*     tapI = reinterpret_cast<int*>(smem + 12800);     // 768 B
    floatx4* tapW = reinterpret_cast<floatx4*>(smem + 13568); // 3072 B

    int lane = threadIdx.x & 63;
    int wv   = threadIdx.x >> 6;
    int c0 = __builtin_amdgcn_readfirstlane(wv << 4);

    int bid = blockIdx.x;
    int n   = bid & 7;
    int m   = bid >> 3;

    // ---- tap setup (vertical: kyo=k-1, kxo=0) from off/mask in ws ----
#define V_DY off[(((size_t)n * 3 + k) * 2 + 0) * HW_ + pixp]
#define V_DX off[(((size_t)n * 3 + k) * 2 + 1) * HW_ + pixp]
    TAP_SETUP_192(V, mask[((size_t)n * 3 + k) * HW_ + pixp], (k - 1), 0)
#undef V_DY
#undef V_DX
    __syncthreads();

    const _Float16* sT = srcT + (size_t)n * (HW_ * 64);
    GATHER_MFMA_BODY(sT)

    // ---- epilogue: out is NCHW f32 (reference layout), nt-stores ----
    int orow = c0 + ((lane >> 4) << 2);
    floatx4 bv = *((const floatx4*)&bias[orow]);
    float* ob = out + ((size_t)n * C_ + orow) * HW_ + m * 64 + col;
    #pragma unroll
    for (int T = 0; T < 4; ++T) {
        __builtin_nontemporal_store(accT[T][0] + bv[0], &ob[T * 16 + (size_t)0 * HW_]);
        __builtin_nontemporal_store(accT[T][1] + bv[1], &ob[T * 16 + (size_t)1 * HW_]);
        __builtin_nontemporal_store(accT[T][2] + bv[2], &ob[T * 16 + (size_t)2 * HW_]);
        __builtin_nontemporal_store(accT[T][3] + bv[3], &ob[T * 16 + (size_t)3 * HW_]);
    }
}

// ---------------------------------------------------------------------------
extern "C" void kernel_launch(void* const* d_in, const int* in_sizes, int n_in,
                              void* d_out, int out_size, void* d_ws, size_t ws_size,
                              hipStream_t stream)
{
    const float* x        = (const float*)d_in[0];
    const float* w_off_h  = (const float*)d_in[1];
    const float* b_off_h  = (const float*)d_in[2];
    const float* w_mask_h = (const float*)d_in[3];
    const float* b_mask_h = (const float*)d_in[4];
    const float* w_off_v  = (const float*)d_in[5];
    const float* b_off_v  = (const float*)d_in[6];
    const float* w_mask_v = (const float*)d_in[7];
    const float* b_mask_v = (const float*)d_in[8];
    const float* w_h      = (const float*)d_in[9];
    const float* b_h      = (const float*)d_in[10];
    const float* w_v      = (const float*)d_in[11];
    const float* b_v      = (const float*)d_in[12];

    // ws: f32 region then f16 region; ~38.3 MB. All gather reads are
    // in-image (base clamped), so no guard zones are needed.
    float* ws      = (float*)d_ws;
    float* off_v   = ws;                    // 786432 f32
    float* mask_v  = off_v  + 786432;       // 393216 f32
    float* wOffAll = mask_v + 393216;       // 3584 f32
    _Float16* xT     = (_Float16*)(wOffAll + 3584);   // 8388608 f16 (x NHWC)
    _Float16* x_hT   = xT + 8388608;                  // 8388608 f16 (x_h NHWC)
    _Float16* wF16_h = x_hT + 8388608;                // 12288 f16
    _Float16* wF16_v = wF16_h + 12288;                // 12288 f16

    prep_kernel<<<110, 256, 0, stream>>>(
        w_off_h, w_mask_h, w_off_v, w_mask_v, w_h, w_v,
        wOffAll, wF16_h, wF16_v);

    dim3 grid(NPIX / 64), block(256);
    transpose_kernel<<<grid, block, 0, stream>>>(x, xT);

    deform_h_kernel<<<grid, block, 0, stream>>>(
        x, xT, wOffAll, b_off_h, b_mask_h, b_off_v, b_mask_v,
        wF16_h, b_h, off_v, mask_v, x_hT);

    deform_v_kernel<<<grid, block, 0, stream>>>(
        x_hT, off_v, mask_v, wF16_v, b_v, (float*)d_out);
}